// Round 10
// baseline (18950.330 us; speedup 1.0000x reference)
//
#include <hip/hip_runtime.h>
#include <math.h>

#define TT 512
#define BB 128
#define HH 1024
#define VV 256
#define NTHR 512
#define NBLK 256
#define RING 262144     // bytes per h ring slot (128 x 1024 fp16 frags)
#define MIRSZ 589824    // mirror slot: [hL0 256K][hL1 256K][p0 64K]

typedef __attribute__((ext_vector_type(4)))  int      i32x4;
typedef __attribute__((ext_vector_type(2)))  _Float16 f16x2;
typedef __attribute__((ext_vector_type(8)))  _Float16 f16x8;
typedef __attribute__((ext_vector_type(16))) float    f32x16;

// LDS layout (bytes)
#define ZEX_OFF  0        // [16][32][33] f32 = 67584
#define WXL_OFF  67584    // [256][33] f32 = 33792 (L0 only)
#define PTAB_OFF 101376   // [64 m][2 oct][2 col][8 j] f16 = 4096
#define PEX_OFF  105472   // [8][128][2] f32 = 8192
#define BIAS_OFF 113664   // 32 f32
#define XID_OFF  113792   // 2 ints (xcc, role)
#define SMEM_SZ  113824

__device__ __forceinline__ float sigf(float x){ return 1.0f/(1.0f+expf(-x)); }
__device__ __forceinline__ void stf(float* p, float v){
  __hip_atomic_store(p, v, __ATOMIC_RELAXED, __HIP_MEMORY_SCOPE_AGENT);
}
__device__ __forceinline__ void st32(unsigned* p, unsigned v){
  __hip_atomic_store(p, v, __ATOMIC_RELAXED, __HIP_MEMORY_SCOPE_AGENT);
}
__device__ __forceinline__ void st64(unsigned long long* p, unsigned long long v){
  __hip_atomic_store(p, v, __ATOMIC_RELAXED, __HIP_MEMORY_SCOPE_AGENT);
}
__device__ __forceinline__ unsigned h2u(_Float16 h){
  union { _Float16 h; unsigned short u; } c; c.h = h; return (unsigned)c.u;
}

__device__ __forceinline__ float dot8(f16x8 a, f16x8 b, float c){
  union { f16x8 v; f16x2 p[4]; } ua, ub;
  ua.v = a; ub.v = b;
#if __has_builtin(__builtin_amdgcn_fdot2)
  c = __builtin_amdgcn_fdot2(ua.p[0], ub.p[0], c, false);
  c = __builtin_amdgcn_fdot2(ua.p[1], ub.p[1], c, false);
  c = __builtin_amdgcn_fdot2(ua.p[2], ub.p[2], c, false);
  c = __builtin_amdgcn_fdot2(ua.p[3], ub.p[3], c, false);
#else
  #pragma unroll
  for (int j=0;j<8;++j) c += (float)a[j]*(float)b[j];
#endif
  return c;
}

// sc1: device-coherent (bypass L1+L2, serve from L3) — for cross-XCD data
#define SCLOAD1(dst, ptr) asm volatile("global_load_dwordx4 %0, %1, off sc1" : "=v"(dst) : "v"(ptr))
// sc0: bypass L1 only, serve from the XCD's L2 — for mirror reads
#define SCLOAD0(dst, ptr) asm volatile("global_load_dwordx4 %0, %1, off sc0" : "=v"(dst) : "v"(ptr))
#define WAITG(Q, N) asm volatile("s_waitcnt vmcnt(" #N ")" \
  : "+v"(Q[0]),"+v"(Q[1]),"+v"(Q[2]),"+v"(Q[3]),"+v"(Q[4]),"+v"(Q[5]),"+v"(Q[6]),"+v"(Q[7]))

// contention-free global barrier: per-block flags, parallel poll, no fences
__device__ __forceinline__ void gbar(unsigned* flags, unsigned rnd, int tid, int bid){
  __syncthreads();   // drains vmcnt: this block's stores are visible (sc1->L3, plain->local L2)
  if (tid == 0) st32(&flags[bid], rnd);
  if (tid < NBLK) {
    int spins = 0;
    while (__hip_atomic_load(&flags[tid], __ATOMIC_RELAXED, __HIP_MEMORY_SCOPE_AGENT) < rnd) {
      __builtin_amdgcn_s_sleep(1);
      if (++spins > (1<<28)) break;
    }
  }
  __syncthreads();
}

// A address: h part (m<64) or L1 K-extension (p0) (m>=64)
#define AADDR(M, HB, EB) (((M) < 64) ? ((HB) + (size_t)(M)*1024) : ((EB) + (size_t)((M)-64)*1024))

#define ISSUE_GRP0(Q, GI) do{ \
  _Pragma("unroll") \
  for (int kk_=0; kk_<4; ++kk_){ \
    const int m_ = kq*NKW + (GI)*4 + kk_; \
    SCLOAD0(Q[kk_],   AADDR(m_, hb0, eb0)); \
    SCLOAD0(Q[kk_+4], AADDR(m_, hb1, eb1)); \
  } }while(0)

#define ISSUE_GRP1(Q, GI) do{ \
  _Pragma("unroll") \
  for (int kk_=0; kk_<4; ++kk_){ \
    const int m_ = kq*NKW + (GI)*4 + kk_; \
    SCLOAD1(Q[kk_],   AADDR(m_, hb0, eb0)); \
    SCLOAD1(Q[kk_+4], AADDR(m_, hb1, eb1)); \
  } }while(0)

#define CONS_GRP(Q, GI) do{ \
  _Pragma("unroll") \
  for (int kk_=0; kk_<4; ++kk_){ \
    const int m_ = kq*NKW + (GI)*4 + kk_; \
    const f16x8 a0_ = __builtin_bit_cast(f16x8, Q[kk_]); \
    const f16x8 a1_ = __builtin_bit_cast(f16x8, Q[kk_+4]); \
    if (gate_on){ \
      acc0 = __builtin_amdgcn_mfma_f32_32x32x16_f16(a0_, breg[(GI)*4+kk_], acc0, 0,0,0); \
      acc1 = __builtin_amdgcn_mfma_f32_32x32x16_f16(a1_, breg[(GI)*4+kk_], acc1, 0,0,0); \
    } \
    if (pf_on && m_ < 64){ \
      const f16x8 t0_ = *(const f16x8*)(smem + PTAB_OFF + (size_t)((m_*2+oct)*2+0)*16); \
      const f16x8 t1_ = *(const f16x8*)(smem + PTAB_OFF + (size_t)((m_*2+oct)*2+1)*16); \
      pacc00 = dot8(a0_, t0_, pacc00); pacc01 = dot8(a0_, t1_, pacc01); \
      pacc10 = dot8(a1_, t0_, pacc10); pacc11 = dot8(a1_, t1_, pacc11); \
    } \
  } }while(0)

// h frag layout (fp16, 256 KB/slot): element (b,k): byte =
//   (b>>5)*65536 + (k>>4)*1024 + ((b&31) + 32*((k>>3)&1))*16 + (k&7)*2
// p0 frags: seq slice t first 64 KB, strip stride 16384.

template<int LAYER>
__device__ __forceinline__ void pipe_body(
    char* smem, const int* __restrict__ x,
    const float* __restrict__ Wgx, const float* __restrict__ Wgh,
    const float* __restrict__ Wix, const float* __restrict__ Wih,
    const float* __restrict__ Wfx, const float* __restrict__ Wfh,
    const float* __restrict__ Wox, const float* __restrict__ Woh,
    const float* __restrict__ Wph,
    const float* __restrict__ bg,  const float* __restrict__ bi,
    const float* __restrict__ bf_, const float* __restrict__ bo,
    const float* __restrict__ bp,
    float* __restrict__ seq,
    char* __restrict__ ring0, char* __restrict__ ring1,
    char* __restrict__ mirror, int mirW,
    int* __restrict__ xTw, unsigned* __restrict__ flags, unsigned* __restrict__ cnt)
{
  const int tid = threadIdx.x, bid = blockIdx.x, gb = bid & 127;
  const int wv = tid>>6, lane = tid&63, oct = lane>>5;
  constexpr int NKW = LAYER ? 20 : 16;
  const int rgp = wv>>2, kq = wv&3;
  const int rg0 = rgp*2, rg1 = rgp*2+1;
  const int jb8 = gb*8, pcol0 = gb*2;
  const int u_row = tid & 127, u_hq = tid>>7;
  char* seqc = (char*)seq;
  char* ringL = LAYER ? ring1 : ring0;

  const float* Wh[4] = { Wgh + (size_t)LAYER*HH*HH, Wih + (size_t)LAYER*HH*HH,
                         Wfh + (size_t)LAYER*HH*HH, Woh + (size_t)LAYER*HH*HH };
  const float* Wx[4] = { Wgx + (size_t)LAYER*VV*HH, Wix + (size_t)LAYER*VV*HH,
                         Wfx + (size_t)LAYER*VV*HH, Wox + (size_t)LAYER*VV*HH };
  const float* bb[4] = { bg + LAYER*HH, bi + LAYER*HH, bf_ + LAYER*HH, bo + LAYER*HH };
  const float* Wph_l = Wph + (size_t)LAYER*HH*VV;
  const float* bp_l  = bp + LAYER*VV;

  float* zex = (float*)(smem + ZEX_OFF);
  float* wxl = (float*)(smem + WXL_OFF);
  float* pex = (float*)(smem + PEX_OFF);
  float* bias_lds = (float*)(smem + BIAS_OFF);
  int*   xid = (int*)(smem + XID_OFF);

  // ---- XCD identity + copy-role election (any bid->XCD mapping works) ----
  int xcc = 0, role = 0;
  if (mirW){
    if (tid == 0){
      unsigned xv = __builtin_amdgcn_s_getreg(63508) & 7u;   // HW_REG_XCC_ID, 32b
      unsigned rv = __hip_atomic_fetch_add(&cnt[xv], 1u,
                      __ATOMIC_RELAXED, __HIP_MEMORY_SCOPE_AGENT) & 31u;
      xid[0] = (int)xv; xid[1] = (int)rv;
    }
    __syncthreads();
    xcc = xid[0]; role = xid[1];
  }
  char* mirX = mirror + (size_t)xcc * (size_t)(mirW>0?mirW:1) * MIRSZ;

  // ---- transpose x[B][T] -> xTw[t][b] (sc1; readers first-touch after barrier) ----
  for (int i = bid*NTHR + tid; i < BB*TT; i += NBLK*NTHR) {
    const int b = i >> 9, t = i & (TT-1);
    __hip_atomic_store(&xTw[t*BB + b], x[i], __ATOMIC_RELAXED, __HIP_MEMORY_SCOPE_AGENT);
  }
  // ---- zero all 4 ring slots (1 MB contiguous from ring0) ----
  for (int idx = bid*NTHR + tid; idx < 262144; idx += NBLK*NTHR)
    stf((float*)ring0 + idx, 0.f);

  // ---- stage gate B-frags into registers (once) ----
  f16x8 breg[NKW];
  #pragma unroll
  for (int i=0;i<NKW;++i){
    const int m = kq*NKW + i;
    const int col = lane&31, gg = col>>3, hc = col&7;
    f16x8 v;
    #pragma unroll
    for (int j=0;j<8;++j){
      const int k = m*16 + oct*8 + j;
      const float w = (k < HH) ? Wh[gg][(size_t)k*HH + jb8 + hc]
                               : Wx[gg][(size_t)(k-HH)*HH + jb8 + hc];
      v[j] = (_Float16)w;
    }
    breg[i] = v;
  }
  // ---- p-weight table (2 pcols) ----
  for (int idx = tid; idx < 64*2*2; idx += NTHR){
    const int m = idx>>2, oc = (idx>>1)&1, cl = idx&1;
    f16x8 v;
    #pragma unroll
    for (int j=0;j<8;++j){
      const int k = m*16 + oc*8 + j;
      v[j] = (_Float16)Wph_l[(size_t)k*VV + pcol0 + cl];
    }
    *(f16x8*)(smem + PTAB_OFF + (size_t)idx*16) = v;
  }
  // ---- L0: token-gather table ----
  if constexpr (LAYER == 0){
    for (int idx = tid; idx < VV*32; idx += NTHR){
      const int vt = idx>>5, c = idx&31, gg = c>>3, hc = c&7;
      wxl[vt*33 + c] = Wx[gg][(size_t)vt*HH + jb8 + hc];
    }
  }
  if (tid < 32) bias_lds[tid] = bb[tid>>3][jb8 + (tid&7)];
  const float bp0 = bp_l[pcol0], bp1 = bp_l[pcol0+1];

  float cst0 = 0.f, cst1 = 0.f;
  unsigned rnd = 0;
  gbar(flags, ++rnd, tid, bid);

  for (int s = 0; s <= TT+2; ++s) {
    const int slot = mirW ? (s & (mirW-1)) : 0;

    // ======== phase 1: refresh this XCD's mirror (role covers 18 KB) ========
    if (mirW){
      char* dst = mirX + (size_t)slot*MIRSZ;
      const char* sH0 = ring0 + (size_t)((s-1)&1)*RING;
      const char* sH1 = ring1 + (size_t)((s-3)&1)*RING;
      const char* sP0 = seqc + (size_t)(s-2)*131072;
      const bool p0ok = (s >= 2 && s <= 513);
      i32x4 v0, v1, v2;
      size_t o0=0, o1=0, o2=0;
      bool k0=false, k1=false, k2=false;
      #define CP_ISSUE(U, V, K, O) { \
        const int unit = (U)*512 + tid; \
        if (unit < 1152){ \
          O = (size_t)(role*1152 + unit)*16; \
          const char* src; bool kk = true; \
          if (O < 262144) src = sH0 + O; \
          else if (O < 524288) src = sH1 + (O - 262144); \
          else { src = sP0 + (O - 524288); kk = p0ok; } \
          if (kk){ SCLOAD1(V, src); K = true; } \
        } }
      CP_ISSUE(0, v0, k0, o0)
      CP_ISSUE(1, v1, k1, o1)
      CP_ISSUE(2, v2, k2, o2)
      #undef CP_ISSUE
      asm volatile("s_waitcnt vmcnt(0)" : "+v"(v0), "+v"(v1), "+v"(v2));
      if (k0) *(i32x4*)(dst + o0) = v0;   // plain stores: land dirty in local L2
      if (k1) *(i32x4*)(dst + o1) = v1;
      if (k2) *(i32x4*)(dst + o2) = v2;
      asm volatile("s_waitcnt vmcnt(0)" ::: "memory");
    }
    gbar(flags, ++rnd, tid, bid);   // mirror complete on every XCD

    // ======== phase 2: compute ========
    const int t = LAYER ? (s-2) : s;
    const bool gate_on = (t >= 0) && (t < TT);
    const bool pf_on   = (t >= 1) && (t <= TT);
    const bool load_on = gate_on || pf_on;

    f32x16 acc0 = {0,0,0,0,0,0,0,0,0,0,0,0,0,0,0,0};
    f32x16 acc1 = {0,0,0,0,0,0,0,0,0,0,0,0,0,0,0,0};
    float pacc00=0.f, pacc01=0.f, pacc10=0.f, pacc11=0.f;
    int tok = 0;

    if (load_on) {
      const char *hb0, *hb1, *eb0, *eb1;
      if (mirW){
        const char* mb = mirX + (size_t)slot*MIRSZ;
        const char* hr = mb + (LAYER ? 262144 : 0);
        hb0 = hr + (size_t)rg0*65536 + (size_t)lane*16;
        hb1 = hr + (size_t)rg1*65536 + (size_t)lane*16;
        eb0 = mb + 524288 + (size_t)rg0*16384 + (size_t)lane*16;
        eb1 = mb + 524288 + (size_t)rg1*16384 + (size_t)lane*16;
      } else {
        const char* hr = ringL + (size_t)((t-1)&1)*RING;
        hb0 = hr + (size_t)rg0*65536 + (size_t)lane*16;
        hb1 = hr + (size_t)rg1*65536 + (size_t)lane*16;
        eb0 = seqc + (size_t)t*131072 + (size_t)rg0*16384 + (size_t)lane*16;
        eb1 = seqc + (size_t)t*131072 + (size_t)rg1*16384 + (size_t)lane*16;
      }
      i32x4 qA[8], qB[8];
      if (LAYER == 0 && gate_on)   // oldest in queue: counted waits stay conservative
        asm volatile("global_load_dword %0, %1, off" : "=v"(tok) : "v"(xTw + t*BB + u_row));

      if (mirW){
        ISSUE_GRP0(qA, 0);
        ISSUE_GRP0(qB, 1);
        WAITG(qA, 8); CONS_GRP(qA, 0); ISSUE_GRP0(qA, 2);
        WAITG(qB, 8); CONS_GRP(qB, 1); ISSUE_GRP0(qB, 3);
        if constexpr (NKW == 20) {
          WAITG(qA, 8); CONS_GRP(qA, 2); ISSUE_GRP0(qA, 4);
          WAITG(qB, 8); CONS_GRP(qB, 3);
          WAITG(qA, 0); CONS_GRP(qA, 4);
        } else {
          WAITG(qA, 8); CONS_GRP(qA, 2);
          WAITG(qB, 0); CONS_GRP(qB, 3);
        }
      } else {
        ISSUE_GRP1(qA, 0);
        ISSUE_GRP1(qB, 1);
        WAITG(qA, 8); CONS_GRP(qA, 0); ISSUE_GRP1(qA, 2);
        WAITG(qB, 8); CONS_GRP(qB, 1); ISSUE_GRP1(qB, 3);
        if constexpr (NKW == 20) {
          WAITG(qA, 8); CONS_GRP(qA, 2); ISSUE_GRP1(qA, 4);
          WAITG(qB, 8); CONS_GRP(qB, 3);
          WAITG(qA, 0); CONS_GRP(qA, 4);
        } else {
          WAITG(qA, 8); CONS_GRP(qA, 2);
          WAITG(qB, 0); CONS_GRP(qB, 3);
        }
      }
      if (LAYER == 0 && gate_on) asm volatile("" : "+v"(tok));

      if (gate_on) {   // gate D partials (D: col=lane&31, row=(r&3)+8*(r>>2)+4*oct)
        const int col = lane&31;
        #pragma unroll
        for (int r=0;r<16;++r){
          const int row = (r&3) + 8*(r>>2) + 4*oct;
          zex[(((rg0*4 + kq)*32) + row)*33 + col] = acc0[r];
          zex[(((rg1*4 + kq)*32) + row)*33 + col] = acc1[r];
        }
      }
      if (pf_on) {
        const int r0 = rg0*32 + (lane&31), r1 = rg1*32 + (lane&31);
        pex[((kq*2+oct)*128 + r0)*2 + 0] = pacc00;
        pex[((kq*2+oct)*128 + r0)*2 + 1] = pacc01;
        pex[((kq*2+oct)*128 + r1)*2 + 0] = pacc10;
        pex[((kq*2+oct)*128 + r1)*2 + 1] = pacc11;
      }
    }
    __syncthreads();

    // ---- LSTM cell update + h store (sc1 -> global ring) ----
    if (gate_on) {
      float hvv[2];
      #pragma unroll
      for (int e=0;e<2;++e){
        const int hc = u_hq*2 + e;
        float z[4];
        #pragma unroll
        for (int g=0; g<4; ++g){
          float sv = bias_lds[g*8 + hc];
          if (LAYER == 0) sv += wxl[tok*33 + g*8 + hc];
          #pragma unroll
          for (int k2=0;k2<4;++k2)
            sv += zex[((((u_row>>5)*4 + k2)*32) + (u_row&31))*33 + g*8 + hc];
          z[g] = sv;
        }
        const float G = tanhf(z[0]), I = sigf(z[1]), F = sigf(z[2]), O = sigf(z[3]);
        float cc = e ? cst1 : cst0;
        cc = fmaf(G, I, cc*F);
        if (e) cst1 = cc; else cst0 = cc;
        hvv[e] = tanhf(cc)*O;
      }
      const int hid0 = jb8 + u_hq*2;
      const size_t off = (size_t)(t&1)*RING + (size_t)(u_row>>5)*65536 + (size_t)(hid0>>4)*1024
                       + (size_t)((u_row&31) + 32*((hid0>>3)&1))*16 + (size_t)(hid0&7)*2;
      st32((unsigned*)(ringL + off), h2u((_Float16)hvv[0]) | (h2u((_Float16)hvv[1])<<16));
    }
    // ---- p finalize for this block's 2 pcols ----
    if (pf_on && tid < 128) {
      const int row = tid;
      float sum0 = bp0, sum1 = bp1;
      #pragma unroll
      for (int i=0;i<8;++i){
        sum0 += pex[(i*128 + row)*2 + 0];
        sum1 += pex[(i*128 + row)*2 + 1];
      }
      if (LAYER == 0) {   // p0 -> fp16 frag region of seq slice t-1
        const size_t off = (size_t)(t-1)*131072 + (size_t)(row>>5)*16384
                         + (size_t)(pcol0>>4)*1024
                         + (size_t)((row&31) + 32*((pcol0>>3)&1))*16 + (size_t)(pcol0&7)*2;
        st32((unsigned*)(seqc + off), h2u((_Float16)sum0) | (h2u((_Float16)sum1)<<16));
      } else {            // p1 -> final fp32 output
        union { float f[2]; unsigned long long u; } pk;
        pk.f[0] = sum0; pk.f[1] = sum1;
        st64((unsigned long long*)(seq + (size_t)(t-1)*BB*VV + (size_t)row*VV + pcol0), pk.u);
      }
    }
    gbar(flags, ++rnd, tid, bid);
  }
}

__global__ __launch_bounds__(NTHR, 1)
void lstm_mir(
    const int*   __restrict__ x,
    const float* __restrict__ Wgx, const float* __restrict__ Wgh,
    const float* __restrict__ Wix, const float* __restrict__ Wih,
    const float* __restrict__ Wfx, const float* __restrict__ Wfh,
    const float* __restrict__ Wox, const float* __restrict__ Woh,
    const float* __restrict__ Wph,
    const float* __restrict__ bg,  const float* __restrict__ bi,
    const float* __restrict__ bf_, const float* __restrict__ bo,
    const float* __restrict__ bp,
    float* __restrict__ seq,
    char* __restrict__ ring0, char* __restrict__ ring1,
    char* __restrict__ mirror, int mirW,
    int* __restrict__ xTw, unsigned* __restrict__ flags, unsigned* __restrict__ cnt)
{
  __shared__ char smem[SMEM_SZ];
  const int bid = blockIdx.x;
  if (bid < 128)
    pipe_body<0>(smem, x, Wgx,Wgh,Wix,Wih,Wfx,Wfh,Wox,Woh,Wph,
                 bg,bi,bf_,bo,bp, seq, ring0, ring1, mirror, mirW, xTw, flags, cnt);
  else
    pipe_body<1>(smem, x, Wgx,Wgh,Wix,Wih,Wfx,Wfh,Wox,Woh,Wph,
                 bg,bi,bf_,bo,bp, seq, ring0, ring1, mirror, mirW, xTw, flags, cnt);
}

extern "C" void kernel_launch(void* const* d_in, const int* in_sizes, int n_in,
                              void* d_out, int out_size, void* d_ws, size_t ws_size,
                              hipStream_t stream)
{
  const int*   x   = (const int*)  d_in[0];
  const float* Wgx = (const float*)d_in[1];
  const float* Wgh = (const float*)d_in[2];
  const float* Wix = (const float*)d_in[3];
  const float* Wih = (const float*)d_in[4];
  const float* Wfx = (const float*)d_in[5];
  const float* Wfh = (const float*)d_in[6];
  const float* Wox = (const float*)d_in[7];
  const float* Woh = (const float*)d_in[8];
  const float* Wph = (const float*)d_in[9];
  const float* bg  = (const float*)d_in[10];
  const float* bi  = (const float*)d_in[11];
  const float* bf  = (const float*)d_in[12];
  const float* bo  = (const float*)d_in[13];
  const float* bp  = (const float*)d_in[14];

  float*    seq   = (float*)d_out;
  char*     base  = (char*)d_ws;
  unsigned* flags = (unsigned*)base;                  // 4 KB
  unsigned* cnt   = (unsigned*)(base + 4096);         // 8 XCD counters (in 4 KB pad)
  int*      xTw   = (int*)(base + 8192);              // 256 KB
  char*     ring0 = base + 8192 + 262144;             // 2 x 256 KB (L0 h ring)
  char*     ring1 = ring0 + 2*RING;                   // 2 x 256 KB (L1 h ring)
  char*     mirror= ring1 + 2*RING;                   // 8 XCD x mirW x 576 KB

  const size_t fixed = 8192 + 262144 + 4*(size_t)RING;
  int mirW;
  if      (ws_size >= fixed + (size_t)2*8*MIRSZ) mirW = 2;
  else if (ws_size >= fixed + (size_t)1*8*MIRSZ) mirW = 1;
  else                                           mirW = 0;  // direct sc1 fallback

  hipMemsetAsync(base, 0, 8192, stream);

  void* args[] = { (void*)&x,
                   (void*)&Wgx, (void*)&Wgh, (void*)&Wix, (void*)&Wih,
                   (void*)&Wfx, (void*)&Wfh, (void*)&Wox, (void*)&Woh,
                   (void*)&Wph,
                   (void*)&bg, (void*)&bi, (void*)&bf, (void*)&bo, (void*)&bp,
                   (void*)&seq, (void*)&ring0, (void*)&ring1,
                   (void*)&mirror, (void*)&mirW,
                   (void*)&xTw, (void*)&flags, (void*)&cnt };

  hipLaunchCooperativeKernel((const void*)lstm_mir, dim3(NBLK), dim3(NTHR),
                             args, 0, stream);
}

// Round 11
// 9292.764 us; speedup vs baseline: 2.0393x; 2.0393x over previous
//
#include <hip/hip_runtime.h>
#include <math.h>

#define TT 512
#define BB 128
#define HH 1024
#define VV 256
#define NTHR 512
#define NBLKA 192          // 64 L0-gate | 32 L0-p | 64 L1-gate | 32 L1-p
#define RING 262144        // bytes per h slot (128 x 1024 fp16 frags)

typedef __attribute__((ext_vector_type(4)))  int      i32x4;
typedef __attribute__((ext_vector_type(8)))  _Float16 f16x8;
typedef __attribute__((ext_vector_type(16))) float    f32x16;

// LDS (gate blocks): abuf 4x16KB | zex [4][128][33] f32 | bias 64 f32
#define ABUF_OFF 0
#define ZEX_OFF  65536
#define BIAS_OFF (65536 + 67584)
#define SMEM_SZ  (65536 + 67584 + 256)   // 133376 B
// p-blocks overlay pex [8][32][33] f32 (33.8 KB) at offset 0.

__device__ __forceinline__ float sigf(float x){ return 1.0f/(1.0f+expf(-x)); }
__device__ __forceinline__ void stf(float* p, float v){
  __hip_atomic_store(p, v, __ATOMIC_RELAXED, __HIP_MEMORY_SCOPE_AGENT);
}
__device__ __forceinline__ void st32(unsigned* p, unsigned v){
  __hip_atomic_store(p, v, __ATOMIC_RELAXED, __HIP_MEMORY_SCOPE_AGENT);
}
__device__ __forceinline__ void st16(unsigned short* p, unsigned short v){
  __hip_atomic_store(p, v, __ATOMIC_RELAXED, __HIP_MEMORY_SCOPE_AGENT);
}
__device__ __forceinline__ unsigned h2u(_Float16 h){
  union { _Float16 h; unsigned short u; } c; c.h = h; return (unsigned)c.u;
}

// device-coherent 16B load (bypasses per-XCD L2; serves from L3 — R6-proven scheme)
#define SCLOAD1(dst, ptr) asm volatile("global_load_dwordx4 %0, %1, off sc1" : "=v"(dst) : "v"(ptr))
// counted wait tied to the two staged regs (dataflow def: consumers can't be hoisted above)
#define WAITN(n, a, b) asm volatile("s_waitcnt vmcnt(" #n ")" : "+v"(a), "+v"(b))
#define WAIT8(Q) asm volatile("s_waitcnt vmcnt(0)" \
  : "+v"(Q[0]),"+v"(Q[1]),"+v"(Q[2]),"+v"(Q[3]),"+v"(Q[4]),"+v"(Q[5]),"+v"(Q[6]),"+v"(Q[7]))

// contention-free grid barrier: per-block flags, parallel poll, no cache fences.
// Leading __syncthreads drains vmcnt -> this block's sc1 stores are device-visible.
__device__ __forceinline__ void gbar(unsigned* flags, unsigned rnd, int tid, int bid){
  __syncthreads();
  if (tid == 0) st32(&flags[bid], rnd);
  if (tid < NBLKA) {
    int spins = 0;
    while (__hip_atomic_load(&flags[tid], __ATOMIC_RELAXED, __HIP_MEMORY_SCOPE_AGENT) < rnd) {
      __builtin_amdgcn_s_sleep(1);
      if (++spins > (1<<28)) break;   // deadlock insurance
    }
  }
  __syncthreads();
}

// h frag layout (fp16, 256 KB/slot): element (b,k) at byte
//   (b>>5)*65536 + (k>>4)*1024 + ((b&31) + 32*((k>>3)&1))*16 + (k&7)*2
// p0 K-ext frags: seq slice t, first 64 KB, strip stride 16384, slab (v>>4)*1024.

// ---------------- gate block: 64 cols (4 gates x 16 hcols), LDS-shared A ----------------
template<int LAYER>
__device__ void gate_body(char* smem, const int gb,
    const int* __restrict__ xTw,
    const float* __restrict__ Wgx, const float* __restrict__ Wgh,
    const float* __restrict__ Wix, const float* __restrict__ Wih,
    const float* __restrict__ Wfx, const float* __restrict__ Wfh,
    const float* __restrict__ Wox, const float* __restrict__ Woh,
    const float* __restrict__ bg,  const float* __restrict__ bi,
    const float* __restrict__ bf_, const float* __restrict__ bo,
    float* __restrict__ seq, char* __restrict__ ringL,
    unsigned* __restrict__ flags)
{
  const int tid = threadIdx.x, bid = blockIdx.x;
  const int wv = tid>>6, lane = tid&63, oct = lane>>5;
  const int tau = wv>>2, kq = wv&3;            // wave = (col-tile, K-quarter)
  constexpr int NC = LAYER ? 20 : 16;          // chunks == slabs per kq
  const int jb16 = gb*16;
  const int u_row = tid&127, hq = tid>>7;
  char* seqc = (char*)seq;
  float* zex = (float*)(smem + ZEX_OFF);
  float* bias_lds = (float*)(smem + BIAS_OFF);

  const float* Wh[4] = { Wgh + (size_t)LAYER*HH*HH, Wih + (size_t)LAYER*HH*HH,
                         Wfh + (size_t)LAYER*HH*HH, Woh + (size_t)LAYER*HH*HH };
  const float* Wx[4] = { Wgx + (size_t)LAYER*VV*HH, Wix + (size_t)LAYER*VV*HH,
                         Wfx + (size_t)LAYER*VV*HH, Wox + (size_t)LAYER*VV*HH };
  const float* bb[4] = { bg + LAYER*HH, bi + LAYER*HH, bf_ + LAYER*HH, bo + LAYER*HH };

  // ---- B-frags in registers: tile tau cols, kq's NC slabs ----
  f16x8 breg[NC];
  #pragma unroll
  for (int i=0;i<NC;++i){
    const int m = kq*NC + i;
    const int col = lane&31, g = col>>3, hc = col&7;
    const int hcol = jb16 + tau*8 + hc;
    f16x8 v;
    #pragma unroll
    for (int j=0;j<8;++j){
      const int k = m*16 + oct*8 + j;
      const float w = (k < HH) ? Wh[g][(size_t)k*HH + hcol]
                               : Wx[g][(size_t)(k-HH)*HH + hcol];
      v[j] = (_Float16)w;
    }
    breg[i] = v;
  }
  if (tid < 64) bias_lds[tid] = bb[tid>>4][jb16 + (tid&15)];

  // staging units: 2 per thread; unit u -> (kq_u = u>>8, strip = (u>>6)&3, l16 = u&63)
  const int u0 = tid*2, u1 = u0+1;
  const int sp0 = (u0>>6)&3, l16_0 = u0&63, kqu0 = u0>>8;
  const int sp1 = (u1>>6)&3, l16_1 = u1&63, kqu1 = u1>>8;
  const int cth0 = 64 - kqu0*NC;   // chunk index where m crosses into K-ext
  const int cth1 = 64 - kqu1*NC;

  float cst[4] = {0.f,0.f,0.f,0.f};
  unsigned rnd = 1;
  gbar(flags, rnd, tid, bid);

  for (int s = 0; s <= TT+2; ++s) {
    const int t = LAYER ? (s-2) : s;
    if (t >= 0 && t < TT) {
      const char* hprev = ringL + (size_t)((t-1)&1)*RING;
      const char* esl   = seqc + (size_t)t*131072;
      const char* bh0 = hprev + (size_t)sp0*65536 + (size_t)(kqu0*NC)*1024 + (size_t)l16_0*16;
      const char* bh1 = hprev + (size_t)sp1*65536 + (size_t)(kqu1*NC)*1024 + (size_t)l16_1*16;
      const char* be0 = esl + (size_t)sp0*16384 + (size_t)l16_0*16;
      const char* be1 = esl + (size_t)sp1*16384 + (size_t)l16_1*16;

      #define ISSUE_C(c, qp) do{ \
        const char* a0_ = ((c) < cth0) ? (bh0 + (size_t)(c)*1024) : (be0 + (size_t)((c)-cth0)*1024); \
        const char* a1_ = ((c) < cth1) ? (bh1 + (size_t)(c)*1024) : (be1 + (size_t)((c)-cth1)*1024); \
        SCLOAD1(qp[0], a0_); SCLOAD1(qp[1], a1_); \
      }while(0)

      int tok = 0;
      if (LAYER == 0){   // oldest in queue -> counted waits stay conservative
        const int* tp = xTw + t*BB + u_row;
        asm volatile("global_load_dword %0, %1, off sc1" : "=v"(tok) : "v"(tp));
      }

      i32x4 qe[3][2];
      ISSUE_C(0, qe[0]); ISSUE_C(1, qe[1]); ISSUE_C(2, qe[2]);
      WAITN(4, qe[0][0], qe[0][1]);
      *(i32x4*)(smem + ABUF_OFF + (size_t)u0*16) = qe[0][0];
      *(i32x4*)(smem + ABUF_OFF + (size_t)u1*16) = qe[0][1];
      __syncthreads();

      f32x16 acc[4];
      #pragma unroll
      for (int sp=0;sp<4;++sp) acc[sp] = (f32x16){0,0,0,0,0,0,0,0,0,0,0,0,0,0,0,0};

      #pragma unroll
      for (int c = 0; c < NC; ++c) {
        const unsigned rb = (unsigned)ABUF_OFF + (unsigned)(c&3)*16384u
                          + (unsigned)kq*4096u + (unsigned)lane*16u;
        i32x4 a0 = *(const i32x4*)(smem + rb + 0*1024);
        i32x4 a1 = *(const i32x4*)(smem + rb + 1*1024);
        i32x4 a2 = *(const i32x4*)(smem + rb + 2*1024);
        i32x4 a3 = *(const i32x4*)(smem + rb + 3*1024);
        if (c+3 < NC) ISSUE_C(c+3, qe[(c+3)%3]);
        acc[0] = __builtin_amdgcn_mfma_f32_32x32x16_f16(__builtin_bit_cast(f16x8,a0), breg[c], acc[0], 0,0,0);
        acc[1] = __builtin_amdgcn_mfma_f32_32x32x16_f16(__builtin_bit_cast(f16x8,a1), breg[c], acc[1], 0,0,0);
        acc[2] = __builtin_amdgcn_mfma_f32_32x32x16_f16(__builtin_bit_cast(f16x8,a2), breg[c], acc[2], 0,0,0);
        acc[3] = __builtin_amdgcn_mfma_f32_32x32x16_f16(__builtin_bit_cast(f16x8,a3), breg[c], acc[3], 0,0,0);
        if (c+1 < NC){
          if (c+3 < NC)      { WAITN(4, qe[(c+1)%3][0], qe[(c+1)%3][1]); }
          else if (c+2 < NC) { WAITN(2, qe[(c+1)%3][0], qe[(c+1)%3][1]); }
          else               { WAITN(0, qe[(c+1)%3][0], qe[(c+1)%3][1]); }
          *(i32x4*)(smem + ABUF_OFF + (size_t)((c+1)&3)*16384 + (size_t)u0*16) = qe[(c+1)%3][0];
          *(i32x4*)(smem + ABUF_OFF + (size_t)((c+1)&3)*16384 + (size_t)u1*16) = qe[(c+1)%3][1];
        }
        __syncthreads();
      }
      #undef ISSUE_C
      if (LAYER == 0) asm volatile("" : "+v"(tok));   // retired by chunk-loop waits

      // ---- per-tile: zex publish -> cell update -> h store (serialized tiles) ----
      #pragma unroll
      for (int tt = 0; tt < 2; ++tt){
        if (tau == tt){
          const int col = lane&31;
          #pragma unroll
          for (int sp=0; sp<4; ++sp){
            #pragma unroll
            for (int r=0;r<16;++r){
              const int row = sp*32 + (r&3) + 8*(r>>2) + 4*oct;
              zex[((kq*128)+row)*33 + col] = acc[sp][r];
            }
          }
        }
        __syncthreads();
        {
          float hv[2];
          #pragma unroll
          for (int e=0;e<2;++e){
            const int hcl = hq*2+e;            // tile-local hcol 0..7
            const int hcl16 = tt*8 + hcl;      // block-local 0..15
            float z[4];
            #pragma unroll
            for (int g=0; g<4; ++g){
              float sv = bias_lds[g*16 + hcl16];
              if (LAYER == 0)                   // read-only input: plain cached, replay-safe
                sv += Wx[g][(size_t)tok*HH + jb16 + hcl16];
              #pragma unroll
              for (int k2=0;k2<4;++k2)
                sv += zex[((k2*128)+u_row)*33 + g*8 + hcl];
              z[g] = sv;
            }
            const float G = tanhf(z[0]), I = sigf(z[1]), F = sigf(z[2]), O = sigf(z[3]);
            float cc = cst[tt*2+e];
            cc = fmaf(G, I, cc*F);
            cst[tt*2+e] = cc;
            hv[e] = tanhf(cc)*O;
          }
          const int hid0 = jb16 + tt*8 + hq*2;
          const size_t off = (size_t)(t&1)*RING + (size_t)(u_row>>5)*65536
                           + (size_t)(hid0>>4)*1024
                           + (size_t)((u_row&31) + 32*((hid0>>3)&1))*16 + (size_t)(hid0&7)*2;
          st32((unsigned*)(ringL + off), h2u((_Float16)hv[0]) | (h2u((_Float16)hv[1])<<16));
        }
        __syncthreads();   // protect zex before next tile's overwrite
      }
    }
    gbar(flags, ++rnd, tid, bid);
  }
}

// ---------------- p block: 32 rows x 32 pcols, full K (R6-proven) ----------------
template<int LAYER>
__device__ void p_body(char* smem, const int pb,
    const float* __restrict__ Wph, const float* __restrict__ bp,
    float* __restrict__ seq, char* __restrict__ ringL,
    unsigned* __restrict__ flags)
{
  const int tid = threadIdx.x, bid = blockIdx.x;
  const int wv = tid>>6, lane = tid&63, oct = lane>>5;
  const int rg_p = pb>>3, cg = pb&7;
  float* pex = (float*)smem;
  const float* Wph_l = Wph + (size_t)LAYER*HH*VV;
  const float* bp_l  = bp + LAYER*VV;
  char* seqc = (char*)seq;

  f16x8 breg[8];
  #pragma unroll
  for (int i=0;i<8;++i){
    const int m = wv*8+i;
    const int pcol = cg*32 + (lane&31);
    f16x8 v;
    #pragma unroll
    for (int j=0;j<8;++j){
      const int k = m*16 + oct*8 + j;
      v[j] = (_Float16)Wph_l[(size_t)k*VV + pcol];
    }
    breg[i] = v;
  }
  float bpv[2];
  #pragma unroll
  for (int e=0;e<2;++e) bpv[e] = bp_l[cg*32 + ((tid + e*512)&31)];

  unsigned rnd = 1;
  gbar(flags, rnd, tid, bid);

  for (int s = 0; s <= TT+2; ++s) {
    const int t = LAYER ? (s-2) : s;
    const bool on = (t >= 1) && (t <= TT);
    if (on) {
      const char* pb0 = ringL + (size_t)((t-1)&1)*RING + (size_t)rg_p*65536 + (size_t)lane*16;
      i32x4 qA[8];
      #pragma unroll
      for (int i=0;i<8;++i) SCLOAD1(qA[i], pb0 + (size_t)(wv*8+i)*1024);
      WAIT8(qA);
      f32x16 accp = {0,0,0,0,0,0,0,0,0,0,0,0,0,0,0,0};
      #pragma unroll
      for (int i=0;i<8;++i)
        accp = __builtin_amdgcn_mfma_f32_32x32x16_f16(__builtin_bit_cast(f16x8,qA[i]), breg[i], accp, 0,0,0);
      const int col = lane&31;
      #pragma unroll
      for (int r=0;r<16;++r){
        const int row = (r&3) + 8*(r>>2) + 4*oct;
        pex[((wv*32)+row)*33 + col] = accp[r];
      }
    }
    __syncthreads();
    if (on) {
      #pragma unroll
      for (int e=0;e<2;++e){
        const int o = tid + e*512;
        const int row = o>>5, col = o&31;
        const int pcol = cg*32 + col;
        float sum = bpv[e];
        #pragma unroll
        for (int w8=0; w8<8; ++w8) sum += pex[((w8*32)+row)*33 + col];
        if (LAYER == 0) {   // p0 -> fp16 frag region of seq slice t-1 (L1 K-ext)
          const size_t off = (size_t)(t-1)*131072 + (size_t)rg_p*16384
                           + (size_t)(pcol>>4)*1024
                           + (size_t)(row + 32*((pcol>>3)&1))*16 + (size_t)(pcol&7)*2;
          st16((unsigned short*)(seqc + off), (unsigned short)h2u((_Float16)sum));
        } else {            // p1 -> final fp32 output
          stf(seq + (size_t)(t-1)*BB*VV + (size_t)(rg_p*32+row)*VV + pcol, sum);
        }
      }
    }
    gbar(flags, ++rnd, tid, bid);
  }
}

__global__ __launch_bounds__(NTHR, 1)
void lstm_v11(
    const int*   __restrict__ x,
    const float* __restrict__ Wgx, const float* __restrict__ Wgh,
    const float* __restrict__ Wix, const float* __restrict__ Wih,
    const float* __restrict__ Wfx, const float* __restrict__ Wfh,
    const float* __restrict__ Wox, const float* __restrict__ Woh,
    const float* __restrict__ Wph,
    const float* __restrict__ bg,  const float* __restrict__ bi,
    const float* __restrict__ bf_, const float* __restrict__ bo,
    const float* __restrict__ bp,
    float* __restrict__ seq,
    char* __restrict__ ring0, char* __restrict__ ring1,
    int* __restrict__ xTw, unsigned* __restrict__ flags)
{
  __shared__ char smem[SMEM_SZ];
  const int tid = threadIdx.x, bid = blockIdx.x;

  // xT transpose (sc1) + zero both rings' both slots (1 MB contiguous from ring0)
  for (int i = bid*NTHR + tid; i < BB*TT; i += NBLKA*NTHR) {
    const int b = i >> 9, t = i & (TT-1);
    __hip_atomic_store(&xTw[t*BB + b], x[i], __ATOMIC_RELAXED, __HIP_MEMORY_SCOPE_AGENT);
  }
  for (int i = bid*NTHR + tid; i < 262144; i += NBLKA*NTHR)
    stf((float*)ring0 + i, 0.f);

  if (bid < 64)
    gate_body<0>(smem, bid, xTw, Wgx,Wgh,Wix,Wih,Wfx,Wfh,Wox,Woh,
                 bg,bi,bf_,bo, seq, ring0, flags);
  else if (bid < 96)
    p_body<0>(smem, bid-64, Wph, bp, seq, ring0, flags);
  else if (bid < 160)
    gate_body<1>(smem, bid-96, xTw, Wgx,Wgh,Wix,Wih,Wfx,Wfh,Wox,Woh,
                 bg,bi,bf_,bo, seq, ring1, flags);
  else
    p_body<1>(smem, bid-160, Wph, bp, seq, ring1, flags);
}

extern "C" void kernel_launch(void* const* d_in, const int* in_sizes, int n_in,
                              void* d_out, int out_size, void* d_ws, size_t ws_size,
                              hipStream_t stream)
{
  const int*   x   = (const int*)  d_in[0];
  const float* Wgx = (const float*)d_in[1];
  const float* Wgh = (const float*)d_in[2];
  const float* Wix = (const float*)d_in[3];
  const float* Wih = (const float*)d_in[4];
  const float* Wfx = (const float*)d_in[5];
  const float* Wfh = (const float*)d_in[6];
  const float* Wox = (const float*)d_in[7];
  const float* Woh = (const float*)d_in[8];
  const float* Wph = (const float*)d_in[9];
  const float* bg  = (const float*)d_in[10];
  const float* bi  = (const float*)d_in[11];
  const float* bf  = (const float*)d_in[12];
  const float* bo  = (const float*)d_in[13];
  const float* bp  = (const float*)d_in[14];

  float*    seq   = (float*)d_out;
  char*     base  = (char*)d_ws;
  unsigned* flags = (unsigned*)base;                  //   4 KB
  int*      xTw   = (int*)(base + 4096);              // 256 KB
  char*     ring0 = base + 4096 + 262144;             // 2 x 256 KB (L0 h)
  char*     ring1 = ring0 + 2*RING;                   // 2 x 256 KB (L1 h)

  hipMemsetAsync(flags, 0, 4096, stream);

  void* args[] = { (void*)&x,
                   (void*)&Wgx, (void*)&Wgh, (void*)&Wix, (void*)&Wih,
                   (void*)&Wfx, (void*)&Wfh, (void*)&Wox, (void*)&Woh,
                   (void*)&Wph,
                   (void*)&bg, (void*)&bi, (void*)&bf, (void*)&bo, (void*)&bp,
                   (void*)&seq, (void*)&ring0, (void*)&ring1,
                   (void*)&xTw, (void*)&flags };

  hipLaunchCooperativeKernel((const void*)lstm_v11, dim3(NBLKA), dim3(NTHR),
                             args, 0, stream);
}

// Round 12
// 8937.569 us; speedup vs baseline: 2.1203x; 1.0397x over previous
//
#include <hip/hip_runtime.h>
#include <math.h>

#define TT 512
#define BB 128
#define HH 1024
#define VV 256
#define NTHR 512
#define NBLKA 192          // 64 L0-gate | 32 L0-p | 64 L1-gate | 32 L1-p
#define RING 262144        // bytes per h slot (128 x 1024 fp16 frags)

typedef __attribute__((ext_vector_type(4)))  int      i32x4;
typedef __attribute__((ext_vector_type(8)))  _Float16 f16x8;
typedef __attribute__((ext_vector_type(16))) float    f32x16;

// LDS (gate blocks): abuf 4x16KB | zex [4][128][33] f32 | bias 64 f32
#define ABUF_OFF 0
#define ZEX_OFF  65536
#define BIAS_OFF (65536 + 67584)
#define SMEM_SZ  (65536 + 67584 + 256)   // 133376 B
// p-blocks overlay pex [8][32][33] f32 (33.8 KB) at offset 0.

__device__ __forceinline__ float sigf(float x){ return 1.0f/(1.0f+expf(-x)); }
__device__ __forceinline__ void stf(float* p, float v){
  __hip_atomic_store(p, v, __ATOMIC_RELAXED, __HIP_MEMORY_SCOPE_AGENT);
}
__device__ __forceinline__ void st32(unsigned* p, unsigned v){
  __hip_atomic_store(p, v, __ATOMIC_RELAXED, __HIP_MEMORY_SCOPE_AGENT);
}
__device__ __forceinline__ void st16(unsigned short* p, unsigned short v){
  __hip_atomic_store(p, v, __ATOMIC_RELAXED, __HIP_MEMORY_SCOPE_AGENT);
}
__device__ __forceinline__ unsigned h2u(_Float16 h){
  union { _Float16 h; unsigned short u; } c; c.h = h; return (unsigned)c.u;
}

// device-coherent 16B load (bypasses per-XCD L2; serves from L3 — R6-proven scheme)
#define SCLOAD1(dst, ptr) asm volatile("global_load_dwordx4 %0, %1, off sc1" : "=v"(dst) : "v"(ptr))
// counted wait tied to the two staged regs (dataflow: the LDS write can't be hoisted above)
#define WAITN(n, a, b) asm volatile("s_waitcnt vmcnt(" #n ")" : "+v"(a), "+v"(b))
#define WAIT8(Q) asm volatile("s_waitcnt vmcnt(0)" \
  : "+v"(Q[0]),"+v"(Q[1]),"+v"(Q[2]),"+v"(Q[3]),"+v"(Q[4]),"+v"(Q[5]),"+v"(Q[6]),"+v"(Q[7]))

// contention-free grid barrier: per-block flags, parallel poll, no cache fences.
__device__ __forceinline__ void gbar(unsigned* flags, unsigned rnd, int tid, int bid){
  __syncthreads();
  if (tid == 0) st32(&flags[bid], rnd);
  if (tid < NBLKA) {
    int spins = 0;
    while (__hip_atomic_load(&flags[tid], __ATOMIC_RELAXED, __HIP_MEMORY_SCOPE_AGENT) < rnd) {
      __builtin_amdgcn_s_sleep(1);
      if (++spins > (1<<28)) break;   // deadlock insurance
    }
  }
  __syncthreads();
}

// h frag layout (fp16, 256 KB/slot): element (b,k) at byte
//   (b>>5)*65536 + (k>>4)*1024 + ((b&31) + 32*((k>>3)&1))*16 + (k&7)*2
// p0 K-ext frags: seq slice t, first 64 KB, strip stride 16384, slab (v>>4)*1024.

// ---------------- gate block: 64 cols (4 gates x 16 hcols), LDS-shared A ----------------
// 6-deep register prefetch queue feeding a 4-buffer LDS chunk pipeline.
template<int LAYER>
__device__ void gate_body(char* smem, const int gb,
    const int* __restrict__ xTw,
    const float* __restrict__ Wgx, const float* __restrict__ Wgh,
    const float* __restrict__ Wix, const float* __restrict__ Wih,
    const float* __restrict__ Wfx, const float* __restrict__ Wfh,
    const float* __restrict__ Wox, const float* __restrict__ Woh,
    const float* __restrict__ bg,  const float* __restrict__ bi,
    const float* __restrict__ bf_, const float* __restrict__ bo,
    float* __restrict__ seq, char* __restrict__ ringL,
    unsigned* __restrict__ flags)
{
  const int tid = threadIdx.x, bid = blockIdx.x;
  const int wv = tid>>6, lane = tid&63, oct = lane>>5;
  const int tau = wv>>2, kq = wv&3;            // wave = (col-tile, K-quarter)
  constexpr int NC = LAYER ? 20 : 16;          // chunks == slabs per kq
  const int jb16 = gb*16;
  const int u_row = tid&127, hq = tid>>7;
  char* seqc = (char*)seq;
  float* zex = (float*)(smem + ZEX_OFF);
  float* bias_lds = (float*)(smem + BIAS_OFF);

  const float* Wh[4] = { Wgh + (size_t)LAYER*HH*HH, Wih + (size_t)LAYER*HH*HH,
                         Wfh + (size_t)LAYER*HH*HH, Woh + (size_t)LAYER*HH*HH };
  const float* Wx[4] = { Wgx + (size_t)LAYER*VV*HH, Wix + (size_t)LAYER*VV*HH,
                         Wfx + (size_t)LAYER*VV*HH, Wox + (size_t)LAYER*VV*HH };
  const float* bb[4] = { bg + LAYER*HH, bi + LAYER*HH, bf_ + LAYER*HH, bo + LAYER*HH };

  // ---- B-frags in registers: tile tau cols, kq's NC slabs ----
  f16x8 breg[NC];
  #pragma unroll
  for (int i=0;i<NC;++i){
    const int m = kq*NC + i;
    const int col = lane&31, g = col>>3, hc = col&7;
    const int hcol = jb16 + tau*8 + hc;
    f16x8 v;
    #pragma unroll
    for (int j=0;j<8;++j){
      const int k = m*16 + oct*8 + j;
      const float w = (k < HH) ? Wh[g][(size_t)k*HH + hcol]
                               : Wx[g][(size_t)(k-HH)*HH + hcol];
      v[j] = (_Float16)w;
    }
    breg[i] = v;
  }
  if (tid < 64) bias_lds[tid] = bb[tid>>4][jb16 + (tid&15)];

  // staging units: 2 per thread; unit u -> (kq_u = u>>8, strip = (u>>6)&3, l16 = u&63)
  const int u0 = tid*2, u1 = u0+1;
  const int sp0 = (u0>>6)&3, l16_0 = u0&63, kqu0 = u0>>8;
  const int sp1 = (u1>>6)&3, l16_1 = u1&63, kqu1 = u1>>8;
  const int cth0 = 64 - kqu0*NC;   // chunk index where m crosses into K-ext
  const int cth1 = 64 - kqu1*NC;

  float cst[4] = {0.f,0.f,0.f,0.f};
  unsigned rnd = 1;
  gbar(flags, rnd, tid, bid);

  for (int s = 0; s <= TT+2; ++s) {
    const int t = LAYER ? (s-2) : s;
    if (t >= 0 && t < TT) {
      const char* hprev = ringL + (size_t)((t-1)&1)*RING;
      const char* esl   = seqc + (size_t)t*131072;
      const char* bh0 = hprev + (size_t)sp0*65536 + (size_t)(kqu0*NC)*1024 + (size_t)l16_0*16;
      const char* bh1 = hprev + (size_t)sp1*65536 + (size_t)(kqu1*NC)*1024 + (size_t)l16_1*16;
      const char* be0 = esl + (size_t)sp0*16384 + (size_t)l16_0*16;
      const char* be1 = esl + (size_t)sp1*16384 + (size_t)l16_1*16;

      #define ISSUE_C(c, qp) do{ \
        const char* a0_ = ((c) < cth0) ? (bh0 + (size_t)(c)*1024) : (be0 + (size_t)((c)-cth0)*1024); \
        const char* a1_ = ((c) < cth1) ? (bh1 + (size_t)(c)*1024) : (be1 + (size_t)((c)-cth1)*1024); \
        SCLOAD1(qp[0], a0_); SCLOAD1(qp[1], a1_); \
      }while(0)

      int tok = 0;
      if (LAYER == 0){   // oldest in queue -> counted waits retire it in the prologue
        const int* tp = xTw + t*BB + u_row;
        asm volatile("global_load_dword %0, %1, off sc1" : "=v"(tok) : "v"(tp));
      }

      // ---- prologue: fill the 6-deep register queue, write chunk 0 ----
      i32x4 qe[6][2];
      ISSUE_C(0, qe[0]); ISSUE_C(1, qe[1]); ISSUE_C(2, qe[2]);
      ISSUE_C(3, qe[3]); ISSUE_C(4, qe[4]); ISSUE_C(5, qe[5]);
      WAITN(10, qe[0][0], qe[0][1]);     // retires tok + chunk0
      *(i32x4*)(smem + ABUF_OFF + (size_t)u0*16) = qe[0][0];
      *(i32x4*)(smem + ABUF_OFF + (size_t)u1*16) = qe[0][1];
      __syncthreads();

      f32x16 acc[4];
      #pragma unroll
      for (int sp=0;sp<4;++sp) acc[sp] = (f32x16){0,0,0,0,0,0,0,0,0,0,0,0,0,0,0,0};

      #pragma unroll
      for (int c = 0; c < NC; ++c) {
        const unsigned rb = (unsigned)ABUF_OFF + (unsigned)(c&3)*16384u
                          + (unsigned)kq*4096u + (unsigned)lane*16u;
        i32x4 a0 = *(const i32x4*)(smem + rb + 0*1024);
        i32x4 a1 = *(const i32x4*)(smem + rb + 1*1024);
        i32x4 a2 = *(const i32x4*)(smem + rb + 2*1024);
        i32x4 a3 = *(const i32x4*)(smem + rb + 3*1024);
        if (c+6 < NC) ISSUE_C(c+6, qe[(c+6)%6]);
        acc[0] = __builtin_amdgcn_mfma_f32_32x32x16_f16(__builtin_bit_cast(f16x8,a0), breg[c], acc[0], 0,0,0);
        acc[1] = __builtin_amdgcn_mfma_f32_32x32x16_f16(__builtin_bit_cast(f16x8,a1), breg[c], acc[1], 0,0,0);
        acc[2] = __builtin_amdgcn_mfma_f32_32x32x16_f16(__builtin_bit_cast(f16x8,a2), breg[c], acc[2], 0,0,0);
        acc[3] = __builtin_amdgcn_mfma_f32_32x32x16_f16(__builtin_bit_cast(f16x8,a3), breg[c], acc[3], 0,0,0);
        if (c+1 < NC){
          i32x4* qn = qe[(c+1)%6];
          if      (c+6 < NC) { WAITN(10, qn[0], qn[1]); }
          else if (c+5 < NC) { WAITN( 8, qn[0], qn[1]); }
          else if (c+4 < NC) { WAITN( 6, qn[0], qn[1]); }
          else if (c+3 < NC) { WAITN( 4, qn[0], qn[1]); }
          else if (c+2 < NC) { WAITN( 2, qn[0], qn[1]); }
          else               { WAITN( 0, qn[0], qn[1]); }
          *(i32x4*)(smem + ABUF_OFF + (size_t)((c+1)&3)*16384 + (size_t)u0*16) = qn[0];
          *(i32x4*)(smem + ABUF_OFF + (size_t)((c+1)&3)*16384 + (size_t)u1*16) = qn[1];
        }
        __syncthreads();
      }
      #undef ISSUE_C
      if (LAYER == 0) asm volatile("" : "+v"(tok));   // retired by prologue wait

      // ---- per-tile: zex publish -> cell update -> h store (serialized tiles) ----
      #pragma unroll
      for (int tt = 0; tt < 2; ++tt){
        if (tau == tt){
          const int col = lane&31;
          #pragma unroll
          for (int sp=0; sp<4; ++sp){
            #pragma unroll
            for (int r=0;r<16;++r){
              const int row = sp*32 + (r&3) + 8*(r>>2) + 4*oct;
              zex[((kq*128)+row)*33 + col] = acc[sp][r];
            }
          }
        }
        __syncthreads();
        {
          float hv[2];
          #pragma unroll
          for (int e=0;e<2;++e){
            const int hcl = hq*2+e;            // tile-local hcol 0..7
            const int hcl16 = tt*8 + hcl;      // block-local 0..15
            float z[4];
            #pragma unroll
            for (int g=0; g<4; ++g){
              float sv = bias_lds[g*16 + hcl16];
              if (LAYER == 0)                   // read-only input: plain cached, replay-safe
                sv += Wx[g][(size_t)tok*HH + jb16 + hcl16];
              #pragma unroll
              for (int k2=0;k2<4;++k2)
                sv += zex[((k2*128)+u_row)*33 + g*8 + hcl];
              z[g] = sv;
            }
            const float G = tanhf(z[0]), I = sigf(z[1]), F = sigf(z[2]), O = sigf(z[3]);
            float cc = cst[tt*2+e];
            cc = fmaf(G, I, cc*F);
            cst[tt*2+e] = cc;
            hv[e] = tanhf(cc)*O;
          }
          const int hid0 = jb16 + tt*8 + hq*2;
          const size_t off = (size_t)(t&1)*RING + (size_t)(u_row>>5)*65536
                           + (size_t)(hid0>>4)*1024
                           + (size_t)((u_row&31) + 32*((hid0>>3)&1))*16 + (size_t)(hid0&7)*2;
          st32((unsigned*)(ringL + off), h2u((_Float16)hv[0]) | (h2u((_Float16)hv[1])<<16));
        }
        __syncthreads();   // protect zex before next tile's overwrite
      }
    }
    gbar(flags, ++rnd, tid, bid);
  }
}

// ---------------- p block: 32 rows x 32 pcols, full K (R6-proven) ----------------
template<int LAYER>
__device__ void p_body(char* smem, const int pb,
    const float* __restrict__ Wph, const float* __restrict__ bp,
    float* __restrict__ seq, char* __restrict__ ringL,
    unsigned* __restrict__ flags)
{
  const int tid = threadIdx.x, bid = blockIdx.x;
  const int wv = tid>>6, lane = tid&63, oct = lane>>5;
  const int rg_p = pb>>3, cg = pb&7;
  float* pex = (float*)smem;
  const float* Wph_l = Wph + (size_t)LAYER*HH*VV;
  const float* bp_l  = bp + LAYER*VV;
  char* seqc = (char*)seq;

  f16x8 breg[8];
  #pragma unroll
  for (int i=0;i<8;++i){
    const int m = wv*8+i;
    const int pcol = cg*32 + (lane&31);
    f16x8 v;
    #pragma unroll
    for (int j=0;j<8;++j){
      const int k = m*16 + oct*8 + j;
      v[j] = (_Float16)Wph_l[(size_t)k*VV + pcol];
    }
    breg[i] = v;
  }
  float bpv[2];
  #pragma unroll
  for (int e=0;e<2;++e) bpv[e] = bp_l[cg*32 + ((tid + e*512)&31)];

  unsigned rnd = 1;
  gbar(flags, rnd, tid, bid);

  for (int s = 0; s <= TT+2; ++s) {
    const int t = LAYER ? (s-2) : s;
    const bool on = (t >= 1) && (t <= TT);
    if (on) {
      const char* pb0 = ringL + (size_t)((t-1)&1)*RING + (size_t)rg_p*65536 + (size_t)lane*16;
      i32x4 qA[8];
      #pragma unroll
      for (int i=0;i<8;++i) SCLOAD1(qA[i], pb0 + (size_t)(wv*8+i)*1024);
      WAIT8(qA);
      f32x16 accp = {0,0,0,0,0,0,0,0,0,0,0,0,0,0,0,0};
      #pragma unroll
      for (int i=0;i<8;++i)
        accp = __builtin_amdgcn_mfma_f32_32x32x16_f16(__builtin_bit_cast(f16x8,qA[i]), breg[i], accp, 0,0,0);
      const int col = lane&31;
      #pragma unroll
      for (int r=0;r<16;++r){
        const int row = (r&3) + 8*(r>>2) + 4*oct;
        pex[((wv*32)+row)*33 + col] = accp[r];
      }
    }
    __syncthreads();
    if (on) {
      #pragma unroll
      for (int e=0;e<2;++e){
        const int o = tid + e*512;
        const int row = o>>5, col = o&31;
        const int pcol = cg*32 + col;
        float sum = bpv[e];
        #pragma unroll
        for (int w8=0; w8<8; ++w8) sum += pex[((w8*32)+row)*33 + col];
        if (LAYER == 0) {   // p0 -> fp16 frag region of seq slice t-1 (L1 K-ext)
          const size_t off = (size_t)(t-1)*131072 + (size_t)rg_p*16384
                           + (size_t)(pcol>>4)*1024
                           + (size_t)(row + 32*((pcol>>3)&1))*16 + (size_t)(pcol&7)*2;
          st16((unsigned short*)(seqc + off), (unsigned short)h2u((_Float16)sum));
        } else {            // p1 -> final fp32 output
          stf(seq + (size_t)(t-1)*BB*VV + (size_t)(rg_p*32+row)*VV + pcol, sum);
        }
      }
    }
    gbar(flags, ++rnd, tid, bid);
  }
}

__global__ __launch_bounds__(NTHR, 1)
void lstm_v12(
    const int*   __restrict__ x,
    const float* __restrict__ Wgx, const float* __restrict__ Wgh,
    const float* __restrict__ Wix, const float* __restrict__ Wih,
    const float* __restrict__ Wfx, const float* __restrict__ Wfh,
    const float* __restrict__ Wox, const float* __restrict__ Woh,
    const float* __restrict__ Wph,
    const float* __restrict__ bg,  const float* __restrict__ bi,
    const float* __restrict__ bf_, const float* __restrict__ bo,
    const float* __restrict__ bp,
    float* __restrict__ seq,
    char* __restrict__ ring0, char* __restrict__ ring1,
    int* __restrict__ xTw, unsigned* __restrict__ flags)
{
  __shared__ char smem[SMEM_SZ];
  const int tid = threadIdx.x, bid = blockIdx.x;

  // xT transpose (sc1) + zero both rings' both slots (1 MB contiguous from ring0)
  for (int i = bid*NTHR + tid; i < BB*TT; i += NBLKA*NTHR) {
    const int b = i >> 9, t = i & (TT-1);
    __hip_atomic_store(&xTw[t*BB + b], x[i], __ATOMIC_RELAXED, __HIP_MEMORY_SCOPE_AGENT);
  }
  for (int i = bid*NTHR + tid; i < 262144; i += NBLKA*NTHR)
    stf((float*)ring0 + i, 0.f);

  if (bid < 64)
    gate_body<0>(smem, bid, xTw, Wgx,Wgh,Wix,Wih,Wfx,Wfh,Wox,Woh,
                 bg,bi,bf_,bo, seq, ring0, flags);
  else if (bid < 96)
    p_body<0>(smem, bid-64, Wph, bp, seq, ring0, flags);
  else if (bid < 160)
    gate_body<1>(smem, bid-96, xTw, Wgx,Wgh,Wix,Wih,Wfx,Wfh,Wox,Woh,
                 bg,bi,bf_,bo, seq, ring1, flags);
  else
    p_body<1>(smem, bid-160, Wph, bp, seq, ring1, flags);
}

extern "C" void kernel_launch(void* const* d_in, const int* in_sizes, int n_in,
                              void* d_out, int out_size, void* d_ws, size_t ws_size,
                              hipStream_t stream)
{
  const int*   x   = (const int*)  d_in[0];
  const float* Wgx = (const float*)d_in[1];
  const float* Wgh = (const float*)d_in[2];
  const float* Wix = (const float*)d_in[3];
  const float* Wih = (const float*)d_in[4];
  const float* Wfx = (const float*)d_in[5];
  const float* Wfh = (const float*)d_in[6];
  const float* Wox = (const float*)d_in[7];
  const float* Woh = (const float*)d_in[8];
  const float* Wph = (const float*)d_in[9];
  const float* bg  = (const float*)d_in[10];
  const float* bi  = (const float*)d_in[11];
  const float* bf  = (const float*)d_in[12];
  const float* bo  = (const float*)d_in[13];
  const float* bp  = (const float*)d_in[14];

  float*    seq   = (float*)d_out;
  char*     base  = (char*)d_ws;
  unsigned* flags = (unsigned*)base;                  //   4 KB
  int*      xTw   = (int*)(base + 4096);              // 256 KB
  char*     ring0 = base + 4096 + 262144;             // 2 x 256 KB (L0 h)
  char*     ring1 = ring0 + 2*RING;                   // 2 x 256 KB (L1 h)

  hipMemsetAsync(flags, 0, 4096, stream);

  void* args[] = { (void*)&x,
                   (void*)&Wgx, (void*)&Wgh, (void*)&Wix, (void*)&Wih,
                   (void*)&Wfx, (void*)&Wfh, (void*)&Wox, (void*)&Woh,
                   (void*)&Wph,
                   (void*)&bg, (void*)&bi, (void*)&bf, (void*)&bo, (void*)&bp,
                   (void*)&seq, (void*)&ring0, (void*)&ring1,
                   (void*)&xTw, (void*)&flags };

  hipLaunchCooperativeKernel((const void*)lstm_v12, dim3(NBLKA), dim3(NTHR),
                             args, 0, stream);
}

// Round 17
// 6379.151 us; speedup vs baseline: 2.9707x; 1.4011x over previous
//
#include <hip/hip_runtime.h>
#include <math.h>

#define TT 512
#define BB 128
#define HH 1024
#define VV 256
#define NTHR 512
#define NBLK 256

typedef __attribute__((ext_vector_type(4)))  int      i32x4;
typedef __attribute__((ext_vector_type(2)))  _Float16 f16x2;
typedef __attribute__((ext_vector_type(8)))  _Float16 f16x8;
typedef __attribute__((ext_vector_type(4)))  float    f32x4;
typedef __attribute__((ext_vector_type(16))) float    f32x16;

// LDS (bytes): abuf 80KB (zex overlays it) | wtab 16KB | pex 8KB | bias
#define ABUF_OFF 0
#define ZEX_OFF  0              // [4 kq][32 row][129] f32 = 66048 (overlay, after GEMM)
#define WTAB_OFF 81920          // [64 m][2 oct][8 c] x 16B = 16384
#define PEX_OFF  98304          // [4 kq][2 oct][32 row][8 c] f32 = 8192
#define BIAS_OFF 106496         // 136 f32
#define SMEM_SZ  107072

__device__ __forceinline__ float sigf(float x){ return 1.0f/(1.0f+expf(-x)); }
__device__ __forceinline__ void st32_sc1(unsigned* p, unsigned v){
  __hip_atomic_store(p, v, __ATOMIC_RELAXED, __HIP_MEMORY_SCOPE_AGENT);
}
__device__ __forceinline__ unsigned ld32_sc1(const unsigned* p){
  return __hip_atomic_load(p, __ATOMIC_RELAXED, __HIP_MEMORY_SCOPE_AGENT);
}
__device__ __forceinline__ void st64_sc1(unsigned long long* p, unsigned long long v){
  __hip_atomic_store(p, v, __ATOMIC_RELAXED, __HIP_MEMORY_SCOPE_AGENT);
}
__device__ __forceinline__ void sti_sc1(int* p, int v){
  __hip_atomic_store(p, v, __ATOMIC_RELAXED, __HIP_MEMORY_SCOPE_AGENT);
}
__device__ __forceinline__ unsigned h2u(_Float16 h){
  union { _Float16 h; unsigned short u; } c; c.h = h; return (unsigned)c.u;
}
__device__ __forceinline__ float dot8(f16x8 a, f16x8 b, float c){
  union { f16x8 v; f16x2 p[4]; } ua, ub;
  ua.v = a; ub.v = b;
#if __has_builtin(__builtin_amdgcn_fdot2)
  c = __builtin_amdgcn_fdot2(ua.p[0], ub.p[0], c, false);
  c = __builtin_amdgcn_fdot2(ua.p[1], ub.p[1], c, false);
  c = __builtin_amdgcn_fdot2(ua.p[2], ub.p[2], c, false);
  c = __builtin_amdgcn_fdot2(ua.p[3], ub.p[3], c, false);
#else
  #pragma unroll
  for (int j=0;j<8;++j) c += (float)a[j]*(float)b[j];
#endif
  return c;
}

// sc1: device-coherent via L3 — ALL cross-block data (R6/R12 replay-proven)
#define SCLOAD1(dst, ptr) asm volatile("global_load_dwordx4 %0, %1, off sc1" : "=v"(dst) : "v"(ptr))
#define WAITV8(V) asm volatile("s_waitcnt vmcnt(0)" \
  : "+v"(V[0]),"+v"(V[1]),"+v"(V[2]),"+v"(V[3]),"+v"(V[4]),"+v"(V[5]),"+v"(V[6]),"+v"(V[7]))
#define WAITV10(V) asm volatile("s_waitcnt vmcnt(0)" \
  : "+v"(V[0]),"+v"(V[1]),"+v"(V[2]),"+v"(V[3]),"+v"(V[4]),"+v"(V[5]),"+v"(V[6]),"+v"(V[7]),"+v"(V[8]),"+v"(V[9]))

// GLOBAL contention-free barrier — 256 blocks, per-block flags, parallel poll.
// EXACTLY the R6/R12 replay-proven sync: the 256-arrival latency masks the
// sc1 store->L3 drain window. (R13-R16 lesson: fast/local barriers expose it.)
__device__ __forceinline__ void gbar(unsigned* flags, unsigned rnd, int tid, int bid){
  __syncthreads();   // drains vmcnt: this block's sc1 stores issued
  if (tid == 0) st32_sc1(&flags[bid], rnd);
  if (tid < NBLK) {
    int spins = 0;
    while (ld32_sc1(&flags[tid]) < rnd) {
      __builtin_amdgcn_s_sleep(1);
      if (++spins > (1<<27)) break;   // deadlock insurance
    }
  }
  __syncthreads();
}

// h frag layout per group-slot (64 KB): element (row,k) at byte
//   (k>>4)*1024 + (row + 32*((k>>3)&1))*16 + (k&7)*2     (row 0..31 strip-local)
// p0 mailbox(t, strip) = seq + t*131072B + strip*32768B (16 KB used), same frag
// formula with k -> vocab col. t-unique: L0 writes (round t+1), L1 reads
// (round t+2), L1 overwrites with p1[t] (round t+3) — each separated by the
// global barrier. No ring reuse, no cross-group race.

template<int LAYER>
__device__ void pipe(char* smem, int role, int strip,
    const int* __restrict__ xTw,
    const float* __restrict__ Wgx, const float* __restrict__ Wgh,
    const float* __restrict__ Wix, const float* __restrict__ Wih,
    const float* __restrict__ Wfx, const float* __restrict__ Wfh,
    const float* __restrict__ Wox, const float* __restrict__ Woh,
    const float* __restrict__ Wph,
    const float* __restrict__ bg,  const float* __restrict__ bi,
    const float* __restrict__ bf_, const float* __restrict__ bo,
    const float* __restrict__ bp,
    float* __restrict__ seq, char* __restrict__ hbufG,
    unsigned* __restrict__ flags)
{
  const int tid = threadIdx.x, bid = blockIdx.x;
  const int wv = tid>>6, lane = tid&63, oct = lane>>5;
  const int tp = wv&1, kq = wv>>1;          // wave = (gate-pair, K-quarter)
  constexpr int NKQ = LAYER ? 20 : 16;      // slabs per K-quarter
  const int colb = role*32;                  // hidden-col base (block owns 32 hcols)
  const int pcb  = role*8;                   // p-col base (block owns 8 pcols)
  const int u_row = tid&31, u_hp = tid>>5;   // update: (row, hcol-pair)
  char* seqc = (char*)seq;

  const float* Wh[4] = { Wgh + (size_t)LAYER*HH*HH, Wih + (size_t)LAYER*HH*HH,
                         Wfh + (size_t)LAYER*HH*HH, Woh + (size_t)LAYER*HH*HH };
  const float* Wx[4] = { Wgx + (size_t)LAYER*VV*HH, Wix + (size_t)LAYER*VV*HH,
                         Wfx + (size_t)LAYER*VV*HH, Wox + (size_t)LAYER*VV*HH };
  const float* bb[4] = { bg + LAYER*HH, bi + LAYER*HH, bf_ + LAYER*HH, bo + LAYER*HH };
  const float* Wph_l = Wph + (size_t)LAYER*HH*VV;
  const float* bp_l  = bp + LAYER*VV;

  float* zex = (float*)(smem + ZEX_OFF);
  float* pex = (float*)(smem + PEX_OFF);
  float* bias_lds = (float*)(smem + BIAS_OFF);

  // ---- B-frags: 2 gates (tp*2, tp*2+1) x NKQ slabs, in registers ----
  f16x8 breg[2][NKQ];
  #pragma unroll
  for (int gl=0; gl<2; ++gl){
    const int gg = tp*2 + gl;
    #pragma unroll
    for (int i=0;i<NKQ;++i){
      const int m = kq*NKQ + i;
      const int col = colb + (lane&31);
      f16x8 v;
      #pragma unroll
      for (int j=0;j<8;++j){
        const int k = m*16 + oct*8 + j;
        const float w = (k < HH) ? Wh[gg][(size_t)k*HH + col]
                                 : Wx[gg][(size_t)(k-HH)*HH + col];
        v[j] = (_Float16)w;
      }
      breg[gl][i] = v;
    }
  }
  // ---- wtab: Wph for this block's 8 pcols, [64 m][2 oct][8 c] ----
  #pragma unroll
  for (int e=0;e<2;++e){
    const int idx = tid*2 + e;              // 0..1023
    const int m = idx>>4, oc = (idx>>3)&1, c = idx&7;
    f16x8 v;
    #pragma unroll
    for (int j=0;j<8;++j){
      const int k = m*16 + oc*8 + j;
      v[j] = (_Float16)Wph_l[(size_t)k*VV + pcb + c];
    }
    *(f16x8*)(smem + WTAB_OFF + (size_t)idx*16) = v;
  }
  if (tid < 128) bias_lds[tid] = bb[tid>>5][colb + (tid&31)];
  if (tid < 8)   bias_lds[128+tid] = bp_l[pcb + tid];

  float cA = 0.f, cB = 0.f;

  for (int s = 0; s <= TT+2; ++s){
    const int t = LAYER ? (s-2) : s;
    const bool gate_on = (t >= 0) && (t < TT);
    const bool pd_on   = (t >= 1) && (t <= TT);   // produces p[t-1]
    const bool st_on   = gate_on || pd_on;

    int tok = 0;
    if (LAYER == 0 && gate_on){   // sc1; retired by stage vmcnt(0)
      const int* tp_ = xTw + t*BB + strip*32 + u_row;
      asm volatile("global_load_dword %0, %1, off sc1" : "=v"(tok) : "v"(tp_));
    }

    // ---- stage A into LDS: all sc1 (device-coherent; replay-proven path) ----
    if (st_on){
      const char* hb = hbufG + (size_t)((t-1)&1)*65536 + (size_t)tid*16;
      if (LAYER == 1 && gate_on){
        const char* mb = seqc + (size_t)t*131072 + (size_t)strip*32768 + (size_t)tid*16;
        i32x4 v[10];
        SCLOAD1(v[0], hb);           SCLOAD1(v[1], hb+8192);
        SCLOAD1(v[2], hb+16384);     SCLOAD1(v[3], hb+24576);
        SCLOAD1(v[4], hb+32768);     SCLOAD1(v[5], hb+40960);
        SCLOAD1(v[6], hb+49152);     SCLOAD1(v[7], hb+57344);
        SCLOAD1(v[8], mb);           SCLOAD1(v[9], mb+8192);
        WAITV10(v);
        #pragma unroll
        for (int i=0;i<10;++i)
          *(i32x4*)(smem + ABUF_OFF + (size_t)tid*16 + (size_t)i*8192) = v[i];
      } else {
        i32x4 v[8];
        SCLOAD1(v[0], hb);           SCLOAD1(v[1], hb+8192);
        SCLOAD1(v[2], hb+16384);     SCLOAD1(v[3], hb+24576);
        SCLOAD1(v[4], hb+32768);     SCLOAD1(v[5], hb+40960);
        SCLOAD1(v[6], hb+49152);     SCLOAD1(v[7], hb+57344);
        WAITV8(v);
        #pragma unroll
        for (int i=0;i<8;++i)
          *(i32x4*)(smem + ABUF_OFF + (size_t)tid*16 + (size_t)i*8192) = v[i];
      }
    }
    if (LAYER == 0 && gate_on) asm volatile("" : "+v"(tok));  // tok retired above
    __syncthreads();

    // ---- GEMM (+ p-dot side-job on the same A) ----
    f32x16 acc0 = {0,0,0,0,0,0,0,0,0,0,0,0,0,0,0,0};
    f32x16 acc1 = {0,0,0,0,0,0,0,0,0,0,0,0,0,0,0,0};
    f32x4  pacc = {0.f,0.f,0.f,0.f};
    if (st_on){
      #pragma unroll
      for (int i=0;i<NKQ;++i){
        const int m = kq*NKQ + i;
        const i32x4 a = *(const i32x4*)(smem + ABUF_OFF + (size_t)m*1024 + (size_t)lane*16);
        const f16x8 af = __builtin_bit_cast(f16x8, a);
        if (gate_on){
          acc0 = __builtin_amdgcn_mfma_f32_32x32x16_f16(af, breg[0][i], acc0, 0,0,0);
          acc1 = __builtin_amdgcn_mfma_f32_32x32x16_f16(af, breg[1][i], acc1, 0,0,0);
        }
        if (pd_on && m < 64){
          const char* wt = smem + WTAB_OFF + (size_t)(((m*2+oct)*8) + tp*4)*16;
          pacc.x = dot8(af, *(const f16x8*)(wt),    pacc.x);
          pacc.y = dot8(af, *(const f16x8*)(wt+16), pacc.y);
          pacc.z = dot8(af, *(const f16x8*)(wt+32), pacc.z);
          pacc.w = dot8(af, *(const f16x8*)(wt+48), pacc.w);
        }
      }
    }
    __syncthreads();   // abuf reads done -> zex overlay safe

    if (gate_on){      // D: col=lane&31, row=(r&3)+8*(r>>2)+4*oct
      const int col = lane&31;
      #pragma unroll
      for (int r=0;r<16;++r){
        const int row = (r&3) + 8*(r>>2) + 4*oct;
        zex[(kq*32+row)*129 + (tp*2+0)*32 + col] = acc0[r];
        zex[(kq*32+row)*129 + (tp*2+1)*32 + col] = acc1[r];
      }
    }
    if (pd_on){
      *(f32x4*)&pex[(((kq*2+oct)*32) + (lane&31))*8 + tp*4] = pacc;
    }
    __syncthreads();

    // ---- LSTM cell update + h store (sc1 -> group ring) ----
    if (gate_on){
      float hv[2];
      #pragma unroll
      for (int e=0;e<2;++e){
        const int hc = u_hp*2 + e;
        float z[4];
        #pragma unroll
        for (int gg=0; gg<4; ++gg){
          float sv = bias_lds[gg*32 + hc];
          if (LAYER == 0) sv += Wx[gg][(size_t)tok*HH + colb + hc];
          #pragma unroll
          for (int k2=0;k2<4;++k2) sv += zex[(k2*32+u_row)*129 + gg*32 + hc];
          z[gg] = sv;
        }
        const float G = tanhf(z[0]), I = sigf(z[1]), F = sigf(z[2]), O = sigf(z[3]);
        float cc = e ? cB : cA;
        cc = fmaf(G, I, cc*F);
        if (e) cB = cc; else cA = cc;
        hv[e] = tanhf(cc)*O;
      }
      const int k0 = colb + u_hp*2;   // even
      const size_t off = (size_t)(t&1)*65536 + (size_t)(k0>>4)*1024
                       + (size_t)(u_row + 32*((k0>>3)&1))*16 + (size_t)(k0&7)*2;
      st32_sc1((unsigned*)(hbufG + off), h2u((_Float16)hv[0]) | (h2u((_Float16)hv[1])<<16));
    }
    // ---- p reduce + store ----
    if (pd_on && tid < 128){
      const int row = tid>>2, cp = tid&3, c0 = cp*2;
      float s0 = bias_lds[128 + c0], s1 = bias_lds[128 + c0 + 1];
      #pragma unroll
      for (int q=0;q<8;++q){      // q = kq2*2+oc
        s0 += pex[(q*32 + row)*8 + c0];
        s1 += pex[(q*32 + row)*8 + c0 + 1];
      }
      if (LAYER == 0){   // p0 -> fp16 mailbox(t-1, strip), sc1
        const int pc0 = pcb + c0;  // even
        const size_t off = (size_t)(t-1)*131072 + (size_t)strip*32768
                         + (size_t)(pc0>>4)*1024
                         + (size_t)(row + 32*((pc0>>3)&1))*16 + (size_t)(pc0&7)*2;
        st32_sc1((unsigned*)(seqc + off), h2u((_Float16)s0) | (h2u((_Float16)s1)<<16));
      } else {           // p1 -> final fp32 output, sc1
        union { float f[2]; unsigned long long u; } pk;
        pk.f[0] = s0; pk.f[1] = s1;
        st64_sc1((unsigned long long*)(seq + (size_t)(t-1)*BB*VV
                  + (size_t)(strip*32 + row)*VV + pcb + c0), pk.u);
      }
    }

    // ---- ONE global barrier per round (R12-proven sync; orders everything) ----
    gbar(flags, (unsigned)(s + 2), tid, bid);
  }
}

__global__ __launch_bounds__(NTHR, 1)
void lstm_strip2(
    const int*   __restrict__ x,
    const float* __restrict__ Wgx, const float* __restrict__ Wgh,
    const float* __restrict__ Wix, const float* __restrict__ Wih,
    const float* __restrict__ Wfx, const float* __restrict__ Wfh,
    const float* __restrict__ Wox, const float* __restrict__ Woh,
    const float* __restrict__ Wph,
    const float* __restrict__ bg,  const float* __restrict__ bi,
    const float* __restrict__ bf_, const float* __restrict__ bo,
    const float* __restrict__ bp,
    float* __restrict__ seq,
    char* __restrict__ hbuf, int* __restrict__ xTw,
    unsigned* __restrict__ flags)
{
  __shared__ char smem[SMEM_SZ];
  const int tid = threadIdx.x, bid = blockIdx.x;

  // Deterministic grouping — no hardware-ID dependence, replay-identical.
  const int g = bid >> 5;        // 0..7
  const int role = bid & 31;     // 0..31
  const int layer = g >> 2;      // 0..1
  const int strip = g & 3;       // 0..3
  char* hbufG = hbuf + (size_t)g * 131072;

  // Zero own role's 2KB slice of EACH h slot (sc1), then global barrier.
  {
    unsigned* z0 = (unsigned*)(hbufG + (size_t)role*2048);
    unsigned* z1 = (unsigned*)(hbufG + 65536 + (size_t)role*2048);
    st32_sc1(&z0[tid], 0u);                // 512 x 4 B = 2 KB (slot 0 slice)
    st32_sc1(&z1[tid], 0u);                // 2 KB (slot 1 slice)
  }
  // xT transpose (sc1, cross-block readable)
  for (int i = bid*NTHR + tid; i < BB*TT; i += NBLK*NTHR) {
    const int b = i >> 9, t = i & (TT-1);
    sti_sc1(&xTw[t*BB + b], x[i]);
  }
  gbar(flags, 1u, tid, bid);   // xT + zeroed rings visible before t=0

  if (layer == 0)
    pipe<0>(smem, role, strip, xTw, Wgx,Wgh,Wix,Wih,Wfx,Wfh,Wox,Woh,Wph,
            bg,bi,bf_,bo,bp, seq, hbufG, flags);
  else
    pipe<1>(smem, role, strip, xTw, Wgx,Wgh,Wix,Wih,Wfx,Wfh,Wox,Woh,Wph,
            bg,bi,bf_,bo,bp, seq, hbufG, flags);
}

extern "C" void kernel_launch(void* const* d_in, const int* in_sizes, int n_in,
                              void* d_out, int out_size, void* d_ws, size_t ws_size,
                              hipStream_t stream)
{
  const int*   x   = (const int*)  d_in[0];
  const float* Wgx = (const float*)d_in[1];
  const float* Wgh = (const float*)d_in[2];
  const float* Wix = (const float*)d_in[3];
  const float* Wih = (const float*)d_in[4];
  const float* Wfx = (const float*)d_in[5];
  const float* Wfh = (const float*)d_in[6];
  const float* Wox = (const float*)d_in[7];
  const float* Woh = (const float*)d_in[8];
  const float* Wph = (const float*)d_in[9];
  const float* bg  = (const float*)d_in[10];
  const float* bi  = (const float*)d_in[11];
  const float* bf  = (const float*)d_in[12];
  const float* bo  = (const float*)d_in[13];
  const float* bp  = (const float*)d_in[14];

  float*    seq   = (float*)d_out;
  char*     base  = (char*)d_ws;
  unsigned* flags = (unsigned*)base;                  // [256]  @0
  int*      xTw   = (int*)(base + 8192);              // 256 KB
  char*     hbuf  = base + 8192 + 262144;             // [8 group][2 slot][64 KB] = 1 MB

  hipMemsetAsync(base, 0, 8192, stream);

  void* args[] = { (void*)&x,
                   (void*)&Wgx, (void*)&Wgh, (void*)&Wix, (void*)&Wih,
                   (void*)&Wfx, (void*)&Wfh, (void*)&Wox, (void*)&Woh,
                   (void*)&Wph,
                   (void*)&bg, (void*)&bi, (void*)&bf, (void*)&bo, (void*)&bp,
                   (void*)&seq, (void*)&hbuf, (void*)&xTw,
                   (void*)&flags };

  hipLaunchCooperativeKernel((const void*)lstm_strip2, dim3(NBLK), dim3(NTHR),
                             args, 0, stream);
}

// Round 18
// 4735.982 us; speedup vs baseline: 4.0014x; 1.3470x over previous
//
#include <hip/hip_runtime.h>
#include <math.h>

#define TT 512
#define BB 128
#define HH 1024
#define VV 256
#define NTHR 512
#define NBLK 256

typedef __attribute__((ext_vector_type(4)))  int      i32x4;
typedef __attribute__((ext_vector_type(2)))  _Float16 f16x2;
typedef __attribute__((ext_vector_type(8)))  _Float16 f16x8;
typedef __attribute__((ext_vector_type(4)))  float    f32x4;
typedef __attribute__((ext_vector_type(16))) float    f32x16;

// LDS (bytes): abuf 80KB (zex overlays it) | wtab 16KB | pex 8KB | bias
#define ABUF_OFF 0
#define ZEX_OFF  0              // [4 kq][32 row][129] f32 = 66048 (overlay, after GEMM)
#define WTAB_OFF 81920          // [64 m][2 oct][8 c] x 16B = 16384
#define PEX_OFF  98304          // [4 kq][2 oct][32 row][8 c] f32 = 8192
#define BIAS_OFF 106496         // 136 f32
#define SMEM_SZ  107072

__device__ __forceinline__ float sigf(float x){ return 1.0f/(1.0f+expf(-x)); }
__device__ __forceinline__ void st32_sc1(unsigned* p, unsigned v){
  __hip_atomic_store(p, v, __ATOMIC_RELAXED, __HIP_MEMORY_SCOPE_AGENT);
}
__device__ __forceinline__ unsigned ld32_sc1(const unsigned* p){
  return __hip_atomic_load(p, __ATOMIC_RELAXED, __HIP_MEMORY_SCOPE_AGENT);
}
__device__ __forceinline__ void st64_sc1(unsigned long long* p, unsigned long long v){
  __hip_atomic_store(p, v, __ATOMIC_RELAXED, __HIP_MEMORY_SCOPE_AGENT);
}
__device__ __forceinline__ void sti_sc1(int* p, int v){
  __hip_atomic_store(p, v, __ATOMIC_RELAXED, __HIP_MEMORY_SCOPE_AGENT);
}
__device__ __forceinline__ unsigned h2u(_Float16 h){
  union { _Float16 h; unsigned short u; } c; c.h = h; return (unsigned)c.u;
}
__device__ __forceinline__ float dot8(f16x8 a, f16x8 b, float c){
  union { f16x8 v; f16x2 p[4]; } ua, ub;
  ua.v = a; ub.v = b;
#if __has_builtin(__builtin_amdgcn_fdot2)
  c = __builtin_amdgcn_fdot2(ua.p[0], ub.p[0], c, false);
  c = __builtin_amdgcn_fdot2(ua.p[1], ub.p[1], c, false);
  c = __builtin_amdgcn_fdot2(ua.p[2], ub.p[2], c, false);
  c = __builtin_amdgcn_fdot2(ua.p[3], ub.p[3], c, false);
#else
  #pragma unroll
  for (int j=0;j<8;++j) c += (float)a[j]*(float)b[j];
#endif
  return c;
}

// sc1: device-coherent via L3 — ALL cross-block data (R6/R12/R17 replay-proven)
#define SCLOAD1(dst, ptr) asm volatile("global_load_dwordx4 %0, %1, off sc1" : "=v"(dst) : "v"(ptr))
#define WAITV8(V) asm volatile("s_waitcnt vmcnt(0)" \
  : "+v"(V[0]),"+v"(V[1]),"+v"(V[2]),"+v"(V[3]),"+v"(V[4]),"+v"(V[5]),"+v"(V[6]),"+v"(V[7]))
#define WAITV10(V) asm volatile("s_waitcnt vmcnt(0)" \
  : "+v"(V[0]),"+v"(V[1]),"+v"(V[2]),"+v"(V[3]),"+v"(V[4]),"+v"(V[5]),"+v"(V[6]),"+v"(V[7]),"+v"(V[8]),"+v"(V[9]))

// Hierarchical leader-epoch GLOBAL barrier (true 256-block ordering, low
// polling traffic). Arrival: each block sc1-stores its flag. Leader (bid 0)
// polls all 256 flags in parallel, then publishes a single monotone epoch.
// Everyone polls ONE address. Strict global ordering preserved (epoch only
// advances after ALL arrivals) — same ordering semantics as R17's barrier,
// ~3x less latency and ~256x less polling traffic.
__device__ __forceinline__ void gbar(unsigned* flags, unsigned* epoch,
                                     unsigned rnd, int tid, int bid){
  __syncthreads();   // drains vmcnt: this block's sc1 stores issued/retired
  if (tid == 0) st32_sc1(&flags[bid], rnd);
  if (bid == 0){
    if (tid < NBLK){
      int spins = 0;
      while (ld32_sc1(&flags[tid]) < rnd){
        __builtin_amdgcn_s_sleep(1);
        if (++spins > (1<<27)) break;   // deadlock insurance
      }
    }
    __syncthreads();                     // all 256 arrivals seen
    if (tid == 0) st32_sc1(epoch, rnd);  // publish
  }
  if (tid == 0){
    int spins = 0;
    while (ld32_sc1(epoch) < rnd){
      __builtin_amdgcn_s_sleep(1);
      if (++spins > (1<<27)) break;
    }
  }
  __syncthreads();   // broadcast epoch observation to the whole block
}

// h frag layout per group-slot (64 KB): element (row,k) at byte
//   (k>>4)*1024 + (row + 32*((k>>3)&1))*16 + (k&7)*2     (row 0..31 strip-local)
// p0 mailbox(t, strip) = seq + t*131072B + strip*32768B (16 KB used), same frag
// formula with k -> vocab col. t-unique: L0 writes (round t+1), L1 reads
// (round t+2), L1 overwrites with p1[t] (round t+3) — each separated by the
// global barrier. No ring reuse, no cross-group race.

template<int LAYER>
__device__ void pipe(char* smem, int role, int strip,
    const int* __restrict__ xTw,
    const float* __restrict__ Wgx, const float* __restrict__ Wgh,
    const float* __restrict__ Wix, const float* __restrict__ Wih,
    const float* __restrict__ Wfx, const float* __restrict__ Wfh,
    const float* __restrict__ Wox, const float* __restrict__ Woh,
    const float* __restrict__ Wph,
    const float* __restrict__ bg,  const float* __restrict__ bi,
    const float* __restrict__ bf_, const float* __restrict__ bo,
    const float* __restrict__ bp,
    float* __restrict__ seq, char* __restrict__ hbufG,
    unsigned* __restrict__ flags, unsigned* __restrict__ epoch)
{
  const int tid = threadIdx.x, bid = blockIdx.x;
  const int wv = tid>>6, lane = tid&63, oct = lane>>5;
  const int tp = wv&1, kq = wv>>1;          // wave = (gate-pair, K-quarter)
  constexpr int NKQ = LAYER ? 20 : 16;      // slabs per K-quarter
  const int colb = role*32;                  // hidden-col base (block owns 32 hcols)
  const int pcb  = role*8;                   // p-col base (block owns 8 pcols)
  const int u_row = tid&31, u_hp = tid>>5;   // update: (row, hcol-pair)
  char* seqc = (char*)seq;

  const float* Wh[4] = { Wgh + (size_t)LAYER*HH*HH, Wih + (size_t)LAYER*HH*HH,
                         Wfh + (size_t)LAYER*HH*HH, Woh + (size_t)LAYER*HH*HH };
  const float* Wx[4] = { Wgx + (size_t)LAYER*VV*HH, Wix + (size_t)LAYER*VV*HH,
                         Wfx + (size_t)LAYER*VV*HH, Wox + (size_t)LAYER*VV*HH };
  const float* bb[4] = { bg + LAYER*HH, bi + LAYER*HH, bf_ + LAYER*HH, bo + LAYER*HH };
  const float* Wph_l = Wph + (size_t)LAYER*HH*VV;
  const float* bp_l  = bp + LAYER*VV;

  float* zex = (float*)(smem + ZEX_OFF);
  float* pex = (float*)(smem + PEX_OFF);
  float* bias_lds = (float*)(smem + BIAS_OFF);

  // ---- B-frags: 2 gates (tp*2, tp*2+1) x NKQ slabs, in registers ----
  f16x8 breg[2][NKQ];
  #pragma unroll
  for (int gl=0; gl<2; ++gl){
    const int gg = tp*2 + gl;
    #pragma unroll
    for (int i=0;i<NKQ;++i){
      const int m = kq*NKQ + i;
      const int col = colb + (lane&31);
      f16x8 v;
      #pragma unroll
      for (int j=0;j<8;++j){
        const int k = m*16 + oct*8 + j;
        const float w = (k < HH) ? Wh[gg][(size_t)k*HH + col]
                                 : Wx[gg][(size_t)(k-HH)*HH + col];
        v[j] = (_Float16)w;
      }
      breg[gl][i] = v;
    }
  }
  // ---- wtab: Wph for this block's 8 pcols, [64 m][2 oct][8 c] ----
  #pragma unroll
  for (int e=0;e<2;++e){
    const int idx = tid*2 + e;              // 0..1023
    const int m = idx>>4, oc = (idx>>3)&1, c = idx&7;
    f16x8 v;
    #pragma unroll
    for (int j=0;j<8;++j){
      const int k = m*16 + oc*8 + j;
      v[j] = (_Float16)Wph_l[(size_t)k*VV + pcb + c];
    }
    *(f16x8*)(smem + WTAB_OFF + (size_t)idx*16) = v;
  }
  if (tid < 128) bias_lds[tid] = bb[tid>>5][colb + (tid&31)];
  if (tid < 8)   bias_lds[128+tid] = bp_l[pcb + tid];

  float cA = 0.f, cB = 0.f;

  for (int s = 0; s <= TT+2; ++s){
    const int t = LAYER ? (s-2) : s;
    const bool gate_on = (t >= 0) && (t < TT);
    const bool pd_on   = (t >= 1) && (t <= TT);   // produces p[t-1]
    const bool st_on   = gate_on || pd_on;

    int tok = 0;
    if (LAYER == 0 && gate_on){   // sc1; retired by stage vmcnt(0)
      const int* tp_ = xTw + t*BB + strip*32 + u_row;
      asm volatile("global_load_dword %0, %1, off sc1" : "=v"(tok) : "v"(tp_));
    }

    // ---- stage A into LDS: all sc1 (device-coherent; replay-proven path) ----
    if (st_on){
      const char* hb = hbufG + (size_t)((t-1)&1)*65536 + (size_t)tid*16;
      if (LAYER == 1 && gate_on){
        const char* mb = seqc + (size_t)t*131072 + (size_t)strip*32768 + (size_t)tid*16;
        i32x4 v[10];
        SCLOAD1(v[0], hb);           SCLOAD1(v[1], hb+8192);
        SCLOAD1(v[2], hb+16384);     SCLOAD1(v[3], hb+24576);
        SCLOAD1(v[4], hb+32768);     SCLOAD1(v[5], hb+40960);
        SCLOAD1(v[6], hb+49152);     SCLOAD1(v[7], hb+57344);
        SCLOAD1(v[8], mb);           SCLOAD1(v[9], mb+8192);
        WAITV10(v);
        #pragma unroll
        for (int i=0;i<10;++i)
          *(i32x4*)(smem + ABUF_OFF + (size_t)tid*16 + (size_t)i*8192) = v[i];
      } else {
        i32x4 v[8];
        SCLOAD1(v[0], hb);           SCLOAD1(v[1], hb+8192);
        SCLOAD1(v[2], hb+16384);     SCLOAD1(v[3], hb+24576);
        SCLOAD1(v[4], hb+32768);     SCLOAD1(v[5], hb+40960);
        SCLOAD1(v[6], hb+49152);     SCLOAD1(v[7], hb+57344);
        WAITV8(v);
        #pragma unroll
        for (int i=0;i<8;++i)
          *(i32x4*)(smem + ABUF_OFF + (size_t)tid*16 + (size_t)i*8192) = v[i];
      }
    }
    if (LAYER == 0 && gate_on) asm volatile("" : "+v"(tok));  // tok retired above
    __syncthreads();

    // ---- GEMM (+ p-dot side-job on the same A) ----
    f32x16 acc0 = {0,0,0,0,0,0,0,0,0,0,0,0,0,0,0,0};
    f32x16 acc1 = {0,0,0,0,0,0,0,0,0,0,0,0,0,0,0,0};
    f32x4  pacc = {0.f,0.f,0.f,0.f};
    if (st_on){
      #pragma unroll
      for (int i=0;i<NKQ;++i){
        const int m = kq*NKQ + i;
        const i32x4 a = *(const i32x4*)(smem + ABUF_OFF + (size_t)m*1024 + (size_t)lane*16);
        const f16x8 af = __builtin_bit_cast(f16x8, a);
        if (gate_on){
          acc0 = __builtin_amdgcn_mfma_f32_32x32x16_f16(af, breg[0][i], acc0, 0,0,0);
          acc1 = __builtin_amdgcn_mfma_f32_32x32x16_f16(af, breg[1][i], acc1, 0,0,0);
        }
        if (pd_on && m < 64){
          const char* wt = smem + WTAB_OFF + (size_t)(((m*2+oct)*8) + tp*4)*16;
          pacc.x = dot8(af, *(const f16x8*)(wt),    pacc.x);
          pacc.y = dot8(af, *(const f16x8*)(wt+16), pacc.y);
          pacc.z = dot8(af, *(const f16x8*)(wt+32), pacc.z);
          pacc.w = dot8(af, *(const f16x8*)(wt+48), pacc.w);
        }
      }
    }
    __syncthreads();   // abuf reads done -> zex overlay safe

    if (gate_on){      // D: col=lane&31, row=(r&3)+8*(r>>2)+4*oct
      const int col = lane&31;
      #pragma unroll
      for (int r=0;r<16;++r){
        const int row = (r&3) + 8*(r>>2) + 4*oct;
        zex[(kq*32+row)*129 + (tp*2+0)*32 + col] = acc0[r];
        zex[(kq*32+row)*129 + (tp*2+1)*32 + col] = acc1[r];
      }
    }
    if (pd_on){
      *(f32x4*)&pex[(((kq*2+oct)*32) + (lane&31))*8 + tp*4] = pacc;
    }
    __syncthreads();

    // ---- LSTM cell update + h store (sc1 -> group ring) ----
    if (gate_on){
      float hv[2];
      #pragma unroll
      for (int e=0;e<2;++e){
        const int hc = u_hp*2 + e;
        float z[4];
        #pragma unroll
        for (int gg=0; gg<4; ++gg){
          float sv = bias_lds[gg*32 + hc];
          if (LAYER == 0) sv += Wx[gg][(size_t)tok*HH + colb + hc];
          #pragma unroll
          for (int k2=0;k2<4;++k2) sv += zex[(k2*32+u_row)*129 + gg*32 + hc];
          z[gg] = sv;
        }
        const float G = tanhf(z[0]), I = sigf(z[1]), F = sigf(z[2]), O = sigf(z[3]);
        float cc = e ? cB : cA;
        cc = fmaf(G, I, cc*F);
        if (e) cB = cc; else cA = cc;
        hv[e] = tanhf(cc)*O;
      }
      const int k0 = colb + u_hp*2;   // even
      const size_t off = (size_t)(t&1)*65536 + (size_t)(k0>>4)*1024
                       + (size_t)(u_row + 32*((k0>>3)&1))*16 + (size_t)(k0&7)*2;
      st32_sc1((unsigned*)(hbufG + off), h2u((_Float16)hv[0]) | (h2u((_Float16)hv[1])<<16));
    }
    // ---- p reduce + store ----
    if (pd_on && tid < 128){
      const int row = tid>>2, cp = tid&3, c0 = cp*2;
      float s0 = bias_lds[128 + c0], s1 = bias_lds[128 + c0 + 1];
      #pragma unroll
      for (int q=0;q<8;++q){      // q = kq2*2+oc
        s0 += pex[(q*32 + row)*8 + c0];
        s1 += pex[(q*32 + row)*8 + c0 + 1];
      }
      if (LAYER == 0){   // p0 -> fp16 mailbox(t-1, strip), sc1
        const int pc0 = pcb + c0;  // even
        const size_t off = (size_t)(t-1)*131072 + (size_t)strip*32768
                         + (size_t)(pc0>>4)*1024
                         + (size_t)(row + 32*((pc0>>3)&1))*16 + (size_t)(pc0&7)*2;
        st32_sc1((unsigned*)(seqc + off), h2u((_Float16)s0) | (h2u((_Float16)s1)<<16));
      } else {           // p1 -> final fp32 output, sc1
        union { float f[2]; unsigned long long u; } pk;
        pk.f[0] = s0; pk.f[1] = s1;
        st64_sc1((unsigned long long*)(seq + (size_t)(t-1)*BB*VV
                  + (size_t)(strip*32 + row)*VV + pcb + c0), pk.u);
      }
    }

    // ---- ONE global leader-epoch barrier per round ----
    gbar(flags, epoch, (unsigned)(s + 2), tid, bid);
  }
}

__global__ __launch_bounds__(NTHR, 1)
void lstm_strip3(
    const int*   __restrict__ x,
    const float* __restrict__ Wgx, const float* __restrict__ Wgh,
    const float* __restrict__ Wix, const float* __restrict__ Wih,
    const float* __restrict__ Wfx, const float* __restrict__ Wfh,
    const float* __restrict__ Wox, const float* __restrict__ Woh,
    const float* __restrict__ Wph,
    const float* __restrict__ bg,  const float* __restrict__ bi,
    const float* __restrict__ bf_, const float* __restrict__ bo,
    const float* __restrict__ bp,
    float* __restrict__ seq,
    char* __restrict__ hbuf, int* __restrict__ xTw,
    unsigned* __restrict__ flags, unsigned* __restrict__ epoch)
{
  __shared__ char smem[SMEM_SZ];
  const int tid = threadIdx.x, bid = blockIdx.x;

  // Deterministic grouping — no hardware-ID dependence, replay-identical.
  const int g = bid >> 5;        // 0..7
  const int role = bid & 31;     // 0..31
  const int layer = g >> 2;      // 0..1
  const int strip = g & 3;       // 0..3
  char* hbufG = hbuf + (size_t)g * 131072;

  // Zero own role's 2KB slice of EACH h slot (sc1), then global barrier.
  {
    unsigned* z0 = (unsigned*)(hbufG + (size_t)role*2048);
    unsigned* z1 = (unsigned*)(hbufG + 65536 + (size_t)role*2048);
    st32_sc1(&z0[tid], 0u);                // 512 x 4 B = 2 KB (slot 0 slice)
    st32_sc1(&z1[tid], 0u);                // 2 KB (slot 1 slice)
  }
  // xT transpose (sc1, cross-block readable)
  for (int i = bid*NTHR + tid; i < BB*TT; i += NBLK*NTHR) {
    const int b = i >> 9, t = i & (TT-1);
    sti_sc1(&xTw[t*BB + b], x[i]);
  }
  gbar(flags, epoch, 1u, tid, bid);   // xT + zeroed rings visible before t=0

  if (layer == 0)
    pipe<0>(smem, role, strip, xTw, Wgx,Wgh,Wix,Wih,Wfx,Wfh,Wox,Woh,Wph,
            bg,bi,bf_,bo,bp, seq, hbufG, flags, epoch);
  else
    pipe<1>(smem, role, strip, xTw, Wgx,Wgh,Wix,Wih,Wfx,Wfh,Wox,Woh,Wph,
            bg,bi,bf_,bo,bp, seq, hbufG, flags, epoch);
}

extern "C" void kernel_launch(void* const* d_in, const int* in_sizes, int n_in,
                              void* d_out, int out_size, void* d_ws, size_t ws_size,
                              hipStream_t stream)
{
  const int*   x   = (const int*)  d_in[0];
  const float* Wgx = (const float*)d_in[1];
  const float* Wgh = (const float*)d_in[2];
  const float* Wix = (const float*)d_in[3];
  const float* Wih = (const float*)d_in[4];
  const float* Wfx = (const float*)d_in[5];
  const float* Wfh = (const float*)d_in[6];
  const float* Wox = (const float*)d_in[7];
  const float* Woh = (const float*)d_in[8];
  const float* Wph = (const float*)d_in[9];
  const float* bg  = (const float*)d_in[10];
  const float* bi  = (const float*)d_in[11];
  const float* bf  = (const float*)d_in[12];
  const float* bo  = (const float*)d_in[13];
  const float* bp  = (const float*)d_in[14];

  float*    seq   = (float*)d_out;
  char*     base  = (char*)d_ws;
  unsigned* flags = (unsigned*)base;                  // [256]  @0
  unsigned* epoch = (unsigned*)(base + 4096);         // single epoch word
  int*      xTw   = (int*)(base + 8192);              // 256 KB
  char*     hbuf  = base + 8192 + 262144;             // [8 group][2 slot][64 KB] = 1 MB

  hipMemsetAsync(base, 0, 8192, stream);

  void* args[] = { (void*)&x,
                   (void*)&Wgx, (void*)&Wgh, (void*)&Wix, (void*)&Wih,
                   (void*)&Wfx, (void*)&Wfh, (void*)&Wox, (void*)&Woh,
                   (void*)&Wph,
                   (void*)&bg, (void*)&bi, (void*)&bf, (void*)&bo, (void*)&bp,
                   (void*)&seq, (void*)&hbuf, (void*)&xTw,
                   (void*)&flags, (void*)&epoch };

  hipLaunchCooperativeKernel((const void*)lstm_strip3, dim3(NBLK), dim3(NTHR),
                             args, 0, stream);
}